// Round 1
// baseline (1301.369 us; speedup 1.0000x reference)
//
#include <hip/hip_runtime.h>

// Problem constants
#define NPTS 4096
#define QN   16384      // B*N
#define KNN  24
#define NCH  8          // knn candidate chunks
#define CS   512        // NPTS/NCH

// ---- workspace offsets (in float units) ----
static constexpr size_t OFF_EDGES = 0;                         // int[QN*24]
static constexpr size_t OFF_BIG   = 393216;
static constexpr size_t OFF_CHD   = OFF_BIG;                   // float[QN*NCH*25]
static constexpr size_t OFF_CHI   = OFF_BIG + 3276800;         // int[QN*NCH*25]
static constexpr size_t OFF_A     = OFF_BIG;                   // float[QN*128] (reuses knn scratch)
static constexpr size_t OFF_C     = OFF_BIG + 2097152;         // float[QN*128]
static constexpr size_t OFF_M     = OFF_BIG + 4194304;         // float[QN*128]
static constexpr size_t OFF_GM    = OFF_BIG + 6553600;         // float[QN*128]
static constexpr size_t OFF_L0    = OFF_GM + 2097152;          // float[QN*64]
static constexpr size_t OFF_L1    = OFF_L0 + 1048576;          // float[QN*128]
static constexpr size_t OFF_L2    = OFF_L1 + 2097152;          // float[QN*256]
static constexpr size_t ST_BASE   = OFF_L2 + 4194304;
static constexpr size_t ST_BN1    = ST_BASE;                   // 256 (sum, sumsq per 128 ch)
static constexpr size_t ST_GM     = ST_BASE + 256;             // 256
static constexpr size_t ST_L0     = ST_BASE + 512;             // 128
static constexpr size_t ST_L1     = ST_BASE + 640;             // 256
static constexpr size_t ST_L2     = ST_BASE + 896;             // 512
static constexpr size_t OFF_PF    = ST_BASE + 1408;            // 1024 uint (point_feat max)
static constexpr size_t OFF_GG    = ST_BASE + 2432;            // 512 uint (graph_glob max)
static constexpr size_t ST_COUNT  = 2944;                      // floats to zero

// order-preserving float<->uint map for atomicMax
__device__ inline unsigned fmap(float f) {
    unsigned u = __float_as_uint(f);
    return (u & 0x80000000u) ? ~u : (u | 0x80000000u);
}
__device__ inline float funmap(unsigned u) {
    unsigned v = (u & 0x80000000u) ? (u & 0x7fffffffu) : ~u;
    return __uint_as_float(v);
}

// ============================================================
// KNN pass 1: per (query, chunk) exact top-25 by distance.
// Distances computed with _rn intrinsics to match numpy's fp32
// evaluation order (self-distance becomes exactly 0).
// Branchless 25-slot sorted (descending) register insertion;
// strict-< + ascending-index feed replicates top_k tie-breaking.
// ============================================================
__global__ __launch_bounds__(256) void knn_chunk_kernel(const float* __restrict__ xyz,
                                                        float* __restrict__ chd,
                                                        int* __restrict__ chi) {
    __shared__ float4 cand[CS];
    int q = blockIdx.x * 256 + threadIdx.x;
    int b = q >> 12, n = q & 4095;
    int chunk = blockIdx.y;
    int j0 = chunk * CS;
    const float* xb = xyz + (size_t)b * 3 * 4096;

    #pragma unroll
    for (int r = 0; r < CS / 256; ++r) {
        int j = r * 256 + threadIdx.x;
        float x = xb[j0 + j], y = xb[4096 + j0 + j], z = xb[8192 + j0 + j];
        float sq = __fadd_rn(__fadd_rn(__fmul_rn(x, x), __fmul_rn(y, y)), __fmul_rn(z, z));
        cand[j] = make_float4(x, y, z, sq);
    }
    __syncthreads();

    float xq = xb[n], yq = xb[4096 + n], zq = xb[8192 + n];
    float sqq = __fadd_rn(__fadd_rn(__fmul_rn(xq, xq), __fmul_rn(yq, yq)), __fmul_rn(zq, zq));

    float d[25]; int id[25];
    #pragma unroll
    for (int s = 0; s < 25; ++s) { d[s] = __builtin_inff(); id[s] = 0x7fffffff; }

    for (int j = 0; j < CS; ++j) {
        float4 cv = cand[j];
        float dot = __fadd_rn(__fadd_rn(__fmul_rn(xq, cv.x), __fmul_rn(yq, cv.y)), __fmul_rn(zq, cv.z));
        float k = __fsub_rn(__fadd_rn(sqq, cv.w), __fmul_rn(2.0f, dot));
        int ki = j0 + j;
        #pragma unroll
        for (int s = 0; s < 24; ++s) {
            bool c1 = d[s + 1] > k;
            bool c2 = d[s] > k;
            float nd = c1 ? d[s + 1] : (c2 ? k : d[s]);
            int   ni = c1 ? id[s + 1] : (c2 ? ki : id[s]);
            d[s] = nd; id[s] = ni;
        }
        bool c2 = d[24] > k;
        d[24]  = c2 ? k  : d[24];
        id[24] = c2 ? ki : id[24];
    }
    // layout [chunk][slot][q] for coalesced write + coalesced merge read
    #pragma unroll
    for (int s = 0; s < 25; ++s) {
        chd[(size_t)(chunk * 25 + s) * QN + q] = d[s];
        chi[(size_t)(chunk * 25 + s) * QN + q] = id[s];
    }
}

// KNN pass 2: merge 8 chunk lists (200 entries) lexicographically
// by (dist, idx); slot 24 = lexicographic min = self -> dropped.
__global__ __launch_bounds__(256) void knn_merge_kernel(const float* __restrict__ chd,
                                                        const int* __restrict__ chi,
                                                        int* __restrict__ edges) {
    int q = blockIdx.x * 256 + threadIdx.x;
    float d[25]; int id[25];
    #pragma unroll
    for (int s = 0; s < 25; ++s) { d[s] = __builtin_inff(); id[s] = 0x7fffffff; }
    for (int e = 0; e < NCH * 25; ++e) {
        float k = chd[(size_t)e * QN + q];
        int  ki = chi[(size_t)e * QN + q];
        #pragma unroll
        for (int s = 0; s < 24; ++s) {
            bool c1 = (d[s + 1] > k) || (d[s + 1] == k && id[s + 1] > ki);
            bool c2 = (d[s] > k)     || (d[s] == k     && id[s] > ki);
            float nd = c1 ? d[s + 1] : (c2 ? k : d[s]);
            int   ni = c1 ? id[s + 1] : (c2 ? ki : id[s]);
            d[s] = nd; id[s] = ni;
        }
        bool c2 = (d[24] > k) || (d[24] == k && id[24] > ki);
        d[24]  = c2 ? k  : d[24];
        id[24] = c2 ? ki : id[24];
    }
    int* eo = edges + (size_t)q * 24;
    #pragma unroll
    for (int s = 0; s < 24; ++s) eo[s] = id[s];
}

// ============================================================
// a = pts·(W1-W2)^T ; c = pts·W2^T   (both [q][128], q = b*4096+n)
// ============================================================
__global__ __launch_bounds__(256) void feat_kernel(const float* __restrict__ pts,
                                                   const float* __restrict__ ec_w,
                                                   float* __restrict__ afeat,
                                                   float* __restrict__ cfeat) {
    __shared__ float inl[64 * 65];
    __shared__ float wa[64 * 132];
    __shared__ float wc[64 * 132];
    int n0 = blockIdx.x * 64;
    int b  = blockIdx.y;

    for (int idx = threadIdx.x; idx < 64 * 64; idx += 256) {
        int c = idx >> 6, p = idx & 63;
        inl[p * 65 + c] = pts[((size_t)(b * 64 + c) << 12) + n0 + p];
    }
    for (int idx = threadIdx.x; idx < 128 * 64; idx += 256) {
        int o = idx >> 6, cc = idx & 63;
        float w1 = ec_w[o * 128 + cc], w2 = ec_w[o * 128 + 64 + cc];
        wa[cc * 132 + o] = w1 - w2;
        wc[cc * 132 + o] = w2;
    }
    __syncthreads();

    int ng = threadIdx.x & 15, og = threadIdx.x >> 4;  // 16x16, OW=8
    float acca[4][8], accc[4][8];
    #pragma unroll
    for (int r = 0; r < 4; ++r)
        #pragma unroll
        for (int i = 0; i < 8; ++i) { acca[r][i] = 0.f; accc[r][i] = 0.f; }

    for (int c = 0; c < 64; ++c) {
        float pv[4];
        #pragma unroll
        for (int r = 0; r < 4; ++r) pv[r] = inl[(ng * 4 + r) * 65 + c];
        const float* wra = &wa[c * 132 + og * 8];
        const float* wrc = &wc[c * 132 + og * 8];
        float4 a0 = *(const float4*)&wra[0];
        float4 a1 = *(const float4*)&wra[4];
        float4 c0 = *(const float4*)&wrc[0];
        float4 c1 = *(const float4*)&wrc[4];
        float wva[8] = {a0.x, a0.y, a0.z, a0.w, a1.x, a1.y, a1.z, a1.w};
        float wvc[8] = {c0.x, c0.y, c0.z, c0.w, c1.x, c1.y, c1.z, c1.w};
        #pragma unroll
        for (int r = 0; r < 4; ++r)
            #pragma unroll
            for (int i = 0; i < 8; ++i) {
                acca[r][i] = fmaf(pv[r], wva[i], acca[r][i]);
                accc[r][i] = fmaf(pv[r], wvc[i], accc[r][i]);
            }
    }
    __syncthreads();
    float* outl = wa;  // reuse
    size_t base = (((size_t)b << 12) + n0) * 128;

    #pragma unroll
    for (int r = 0; r < 4; ++r)
        #pragma unroll
        for (int i = 0; i < 8; ++i)
            outl[(ng * 4 + r) * 132 + og * 8 + i] = acca[r][i];
    __syncthreads();
    for (int idx = threadIdx.x; idx < 64 * 128; idx += 256) {
        int p = idx >> 7, o = idx & 127;
        afeat[base + idx] = outl[p * 132 + o];
    }
    __syncthreads();
    #pragma unroll
    for (int r = 0; r < 4; ++r)
        #pragma unroll
        for (int i = 0; i < 8; ++i)
            outl[(ng * 4 + r) * 132 + og * 8 + i] = accc[r][i];
    __syncthreads();
    for (int idx = threadIdx.x; idx < 64 * 128; idx += 256) {
        int p = idx >> 7, o = idx & 127;
        cfeat[base + idx] = outl[p * 132 + o];
    }
}

// ============================================================
// Neighbor gather: M = a + max_k c[e_k]; BN1 stats from
// sum_k h = 24a+s, sum_k h^2 = 24a^2+2as+q.
// ============================================================
__global__ __launch_bounds__(256) void gather_stats_kernel(const float* __restrict__ afeat,
                                                           const float* __restrict__ cfeat,
                                                           const int* __restrict__ edges,
                                                           float* __restrict__ M,
                                                           float* __restrict__ st) {
    __shared__ int eL[16 * KNN];
    __shared__ float red[256];
    int q0 = blockIdx.x * 16;
    for (int idx = threadIdx.x; idx < 16 * KNN; idx += 256) eL[idx] = edges[(size_t)q0 * KNN + idx];
    __syncthreads();

    int o = threadIdx.x & 127, half = threadIdx.x >> 7;
    float s1 = 0.f, s2 = 0.f;
    for (int pi = 0; pi < 8; ++pi) {
        int p = half * 8 + pi;
        int q = q0 + p;
        int bbase = (q >> 12) << 12;
        float mx = -__builtin_inff(), sv = 0.f, qv = 0.f;
        #pragma unroll 4
        for (int k = 0; k < KNN; ++k) {
            int e = eL[p * KNN + k];
            float v = cfeat[((size_t)(bbase + e) << 7) + o];
            mx = fmaxf(mx, v);
            sv += v;
            qv = fmaf(v, v, qv);
        }
        float a = afeat[((size_t)q << 7) + o];
        M[((size_t)q << 7) + o] = a + mx;
        s1 += fmaf(24.f, a, sv);
        s2 += 24.f * a * a + 2.f * a * sv + qv;
    }
    red[threadIdx.x] = s1; __syncthreads();
    if (half == 0) atomicAdd(&st[o], red[o] + red[128 + o]);
    __syncthreads();
    red[threadIdx.x] = s2; __syncthreads();
    if (half == 0) atomicAdd(&st[128 + o], red[o] + red[128 + o]);
}

// ============================================================
// Generic layer: (optional BN+act on input) -> x·W^T (+bias) ->
// write raw output + accumulate per-channel (sum, sumsq) stats.
// MODE: 0 = concat(xyz,pts) input (no norm), 1 = relu norm-in,
//       2 = leaky norm-in.
// Block: 64 points; thread tile: 4 points x O/16 outputs.
// ============================================================
template<int I, int O, int MODE>
__global__ __launch_bounds__(256) void layer_kernel(
    const float* __restrict__ inraw, const float* __restrict__ inst, float rcnt,
    const float* __restrict__ ing, const float* __restrict__ inbe,
    const float* __restrict__ W, const float* __restrict__ bias,
    const float* __restrict__ xyz, const float* __restrict__ pts,
    float* __restrict__ outraw, float* __restrict__ outst)
{
    constexpr int IP = (I & 1) ? I : I + 1;   // odd stride: conflict-friendly
    constexpr int OP = O + 4;                 // mult-of-4 stride: b128-aligned
    constexpr int OW = O / 16;
    __shared__ float inl[64 * IP];
    __shared__ float wl[64 * OP];
    __shared__ float ns[I], nb[I];

    int q0 = blockIdx.x * 64;

    if (MODE != 0) {
        if (threadIdx.x < I) {
            int c = threadIdx.x;
            float m = inst[c] * rcnt;
            float v = inst[I + c] * rcnt - m * m;
            float inv = 1.0f / sqrtf(v + 1e-5f);
            float sc = inv * ing[c];
            ns[c] = sc;
            nb[c] = inbe[c] - m * sc;
        }
        __syncthreads();
        const float* src = inraw + (size_t)q0 * I;
        for (int idx = threadIdx.x; idx < 64 * I; idx += 256) {
            int p = idx / I, c = idx - p * I;
            float v = fmaf(src[idx], ns[c], nb[c]);
            if (MODE == 1) v = fmaxf(v, 0.0f);
            else           v = (v > 0.0f) ? v : 0.2f * v;
            inl[p * IP + c] = v;
        }
    } else {
        int b = q0 >> 12, n0 = q0 & 4095;
        for (int idx = threadIdx.x; idx < 64 * I; idx += 256) {
            int c = idx >> 6, p = idx & 63;
            float v;
            if (c < 3) v = xyz[((size_t)(b * 3 + c) << 12) + n0 + p];
            else       v = pts[((size_t)(b * 64 + (c - 3)) << 12) + n0 + p];
            inl[p * IP + c] = v;
        }
    }

    int ng = threadIdx.x & 15, og = threadIdx.x >> 4;
    float acc[4][OW];
    #pragma unroll
    for (int r = 0; r < 4; ++r)
        #pragma unroll
        for (int i = 0; i < OW; ++i) acc[r][i] = 0.f;

    for (int ct = 0; ct < I; ct += 64) {
        int CT = (I - ct < 64) ? (I - ct) : 64;
        __syncthreads();  // inl ready (iter 0) / previous wl consumed
        for (int idx = threadIdx.x; idx < CT * O; idx += 256) {
            int o = idx / CT, cc = idx - o * CT;
            wl[cc * OP + o] = W[(size_t)o * I + ct + cc];
        }
        __syncthreads();
        for (int cc = 0; cc < CT; ++cc) {
            int c = ct + cc;
            float pv[4];
            #pragma unroll
            for (int r = 0; r < 4; ++r) pv[r] = inl[(ng * 4 + r) * IP + c];
            const float* wr = &wl[cc * OP + og * OW];
            #pragma unroll
            for (int i4 = 0; i4 < OW / 4; ++i4) {
                float4 wv = *(const float4*)&wr[i4 * 4];
                #pragma unroll
                for (int r = 0; r < 4; ++r) {
                    acc[r][i4 * 4 + 0] = fmaf(pv[r], wv.x, acc[r][i4 * 4 + 0]);
                    acc[r][i4 * 4 + 1] = fmaf(pv[r], wv.y, acc[r][i4 * 4 + 1]);
                    acc[r][i4 * 4 + 2] = fmaf(pv[r], wv.z, acc[r][i4 * 4 + 2]);
                    acc[r][i4 * 4 + 3] = fmaf(pv[r], wv.w, acc[r][i4 * 4 + 3]);
                }
            }
        }
    }

    if (bias != nullptr) {
        #pragma unroll
        for (int i = 0; i < OW; ++i) {
            float bv = bias[og * OW + i];
            #pragma unroll
            for (int r = 0; r < 4; ++r) acc[r][i] += bv;
        }
    }
    __syncthreads();
    // stage outputs (reuse wl) for coalesced store + stats
    #pragma unroll
    for (int r = 0; r < 4; ++r)
        #pragma unroll
        for (int i = 0; i < OW; ++i)
            wl[(ng * 4 + r) * OP + og * OW + i] = acc[r][i];
    __syncthreads();

    float* dst = outraw + (size_t)q0 * O;
    for (int idx = threadIdx.x; idx < 64 * O; idx += 256) {
        int p = idx / O, o = idx - p * O;
        dst[idx] = wl[p * OP + o];
    }
    if (threadIdx.x < O) {
        int o = threadIdx.x;
        float s1 = 0.f, s2 = 0.f;
        #pragma unroll 8
        for (int p = 0; p < 64; ++p) {
            float v = wl[p * OP + o];
            s1 += v;
            s2 = fmaf(v, v, s2);
        }
        atomicAdd(&outst[o], s1);
        atomicAdd(&outst[O + o], s2);
    }
}

// ============================================================
// BN + activation + max over points -> atomicMax (mapped uint)
// ACT: 1 = relu, 0 = leaky
// ============================================================
template<int O, int ACT>
__global__ __launch_bounds__(256) void finalize_max_kernel(const float* __restrict__ raw,
                                                           const float* __restrict__ st, float rcnt,
                                                           const float* __restrict__ g,
                                                           const float* __restrict__ be,
                                                           unsigned* __restrict__ outmax) {
    constexpr int R = 256 / O;
    int b = blockIdx.y;
    int p0 = blockIdx.x * 256;
    int o = threadIdx.x & (O - 1);
    int rep = threadIdx.x / O;
    float m = st[o] * rcnt;
    float v = st[O + o] * rcnt - m * m;
    float inv = 1.0f / sqrtf(v + 1e-5f);
    float sc = inv * g[o];
    float sh = be[o] - m * sc;
    float mx = -__builtin_inff();
    for (int p = rep; p < 256; p += R) {
        float x = fmaf(raw[(size_t)(b * 4096 + p0 + p) * O + o], sc, sh);
        x = ACT ? fmaxf(x, 0.0f) : (x > 0.0f ? x : 0.2f * x);
        mx = fmaxf(mx, x);
    }
    atomicMax(&outmax[b * O + o], fmap(mx));
}

// ============================================================
// Final head: fused(384)·fu_w^T -> BN over B=4 -> leaky -> out
// ============================================================
__global__ __launch_bounds__(256) void final_kernel(const unsigned* __restrict__ pf,
                                                    const unsigned* __restrict__ gg,
                                                    const float* __restrict__ fu_w,
                                                    const float* __restrict__ fu_g,
                                                    const float* __restrict__ fu_b,
                                                    float* __restrict__ out) {
    __shared__ float fl[4 * 384];
    for (int idx = threadIdx.x; idx < 4 * 384; idx += 256) {
        int b = idx / 384, c = idx - b * 384;
        unsigned u = (c < 256) ? pf[b * 256 + c] : gg[b * 128 + (c - 256)];
        fl[idx] = funmap(u);
    }
    __syncthreads();
    int o = threadIdx.x;
    float f[4];
    #pragma unroll
    for (int b = 0; b < 4; ++b) {
        float acc = 0.f;
        for (int c = 0; c < 384; ++c) acc = fmaf(fl[b * 384 + c], fu_w[(size_t)o * 384 + c], acc);
        f[b] = acc;
    }
    float m = 0.25f * (f[0] + f[1] + f[2] + f[3]);
    float var = 0.f;
    #pragma unroll
    for (int b = 0; b < 4; ++b) { float t = f[b] - m; var = fmaf(t, t, var); }
    var *= 0.25f;
    float inv = 1.0f / sqrtf(var + 1e-5f);
    float gv = fu_g[o], bv = fu_b[o];
    #pragma unroll
    for (int b = 0; b < 4; ++b) {
        float x = (f[b] - m) * inv * gv + bv;
        x = (x > 0.0f) ? x : 0.2f * x;
        out[b * 256 + o] = x;
    }
}

extern "C" void kernel_launch(void* const* d_in, const int* in_sizes, int n_in,
                              void* d_out, int out_size, void* d_ws, size_t ws_size,
                              hipStream_t stream) {
    const float* xyz   = (const float*)d_in[0];
    const float* pts   = (const float*)d_in[1];
    const float* ec_w  = (const float*)d_in[2];
    const float* ec_g  = (const float*)d_in[3];
    const float* ec_b  = (const float*)d_in[4];
    const float* gm_w  = (const float*)d_in[5];
    const float* gm_g  = (const float*)d_in[6];
    const float* gm_b  = (const float*)d_in[7];
    const float* w0    = (const float*)d_in[8];
    const float* bias0 = (const float*)d_in[9];
    const float* g0    = (const float*)d_in[10];
    const float* be0   = (const float*)d_in[11];
    const float* w1    = (const float*)d_in[12];
    const float* bias1 = (const float*)d_in[13];
    const float* g1    = (const float*)d_in[14];
    const float* be1   = (const float*)d_in[15];
    const float* w2    = (const float*)d_in[16];
    const float* bias2 = (const float*)d_in[17];
    const float* g2    = (const float*)d_in[18];
    const float* be2   = (const float*)d_in[19];
    const float* fu_w  = (const float*)d_in[20];
    const float* fu_g  = (const float*)d_in[21];
    const float* fu_b  = (const float*)d_in[22];

    float* ws = (float*)d_ws;
    float* out = (float*)d_out;

    // zero stats + atomic-max buffers
    hipMemsetAsync(ws + ST_BASE, 0, ST_COUNT * sizeof(float), stream);

    // KNN
    knn_chunk_kernel<<<dim3(QN / 256, NCH), 256, 0, stream>>>(xyz, ws + OFF_CHD, (int*)(ws + OFF_CHI));
    knn_merge_kernel<<<QN / 256, 256, 0, stream>>>(ws + OFF_CHD, (int*)(ws + OFF_CHI), (int*)(ws + OFF_EDGES));

    // edge-conv decomposition
    feat_kernel<<<dim3(64, 4), 256, 0, stream>>>(pts, ec_w, ws + OFF_A, ws + OFF_C);
    gather_stats_kernel<<<QN / 16, 256, 0, stream>>>(ws + OFF_A, ws + OFF_C, (int*)(ws + OFF_EDGES),
                                                     ws + OFF_M, ws + ST_BN1);

    // graph MLP: leaky(bn1(M)) @ gm_w^T -> gmraw + stats
    layer_kernel<128, 128, 2><<<QN / 64, 256, 0, stream>>>(
        ws + OFF_M, ws + ST_BN1, 1.0f / 393216.0f, ec_g, ec_b,
        gm_w, nullptr, nullptr, nullptr, ws + OFF_GM, ws + ST_GM);

    // point MLP
    layer_kernel<67, 64, 0><<<QN / 64, 256, 0, stream>>>(
        nullptr, nullptr, 0.f, nullptr, nullptr,
        w0, bias0, xyz, pts, ws + OFF_L0, ws + ST_L0);
    layer_kernel<64, 128, 1><<<QN / 64, 256, 0, stream>>>(
        ws + OFF_L0, ws + ST_L0, 1.0f / 16384.0f, g0, be0,
        w1, bias1, nullptr, nullptr, ws + OFF_L1, ws + ST_L1);
    layer_kernel<128, 256, 1><<<QN / 64, 256, 0, stream>>>(
        ws + OFF_L1, ws + ST_L1, 1.0f / 16384.0f, g1, be1,
        w2, bias2, nullptr, nullptr, ws + OFF_L2, ws + ST_L2);

    // reductions to per-batch features
    finalize_max_kernel<128, 0><<<dim3(16, 4), 256, 0, stream>>>(
        ws + OFF_GM, ws + ST_GM, 1.0f / 16384.0f, gm_g, gm_b, (unsigned*)(ws + OFF_GG));
    finalize_max_kernel<256, 1><<<dim3(16, 4), 256, 0, stream>>>(
        ws + OFF_L2, ws + ST_L2, 1.0f / 16384.0f, g2, be2, (unsigned*)(ws + OFF_PF));

    // fused head
    final_kernel<<<1, 256, 0, stream>>>((unsigned*)(ws + OFF_PF), (unsigned*)(ws + OFF_GG),
                                        fu_w, fu_g, fu_b, out);
}

// Round 2
// 563.300 us; speedup vs baseline: 2.3103x; 2.3103x over previous
//
#include <hip/hip_runtime.h>

// Problem constants
#define NPTS 4096
#define QN   16384      // B*N
#define KNN  24

// ---- workspace offsets (in float units) ----
static constexpr size_t OFF_EDGES = 0;                         // int[QN*24]
static constexpr size_t OFF_BIG   = 393216;
static constexpr size_t OFF_A     = OFF_BIG;                   // float[QN*128]
static constexpr size_t OFF_C     = OFF_BIG + 2097152;         // float[QN*128]
static constexpr size_t OFF_M     = OFF_BIG + 4194304;         // float[QN*128]
static constexpr size_t OFF_GM    = OFF_BIG + 6553600;         // float[QN*128]
static constexpr size_t OFF_L0    = OFF_GM + 2097152;          // float[QN*64]
static constexpr size_t OFF_L1    = OFF_L0 + 1048576;          // float[QN*128]
static constexpr size_t OFF_L2    = OFF_L1 + 2097152;          // float[QN*256]
static constexpr size_t ST_BASE   = OFF_L2 + 4194304;
static constexpr size_t ST_BN1    = ST_BASE;                   // 256 (sum, sumsq per 128 ch)
static constexpr size_t ST_GM     = ST_BASE + 256;             // 256
static constexpr size_t ST_L0     = ST_BASE + 512;             // 128
static constexpr size_t ST_L1     = ST_BASE + 640;             // 256
static constexpr size_t ST_L2     = ST_BASE + 896;             // 512
static constexpr size_t OFF_PF    = ST_BASE + 1408;            // 1024 uint (point_feat max)
static constexpr size_t OFF_GG    = ST_BASE + 2432;            // 512 uint (graph_glob max)
static constexpr size_t ST_COUNT  = 2944;                      // floats to zero

// order-preserving float<->uint map (handles possible tiny-negative dists)
__device__ inline unsigned fmap(float f) {
    unsigned u = __float_as_uint(f);
    return (u & 0x80000000u) ? ~u : (u | 0x80000000u);
}
__device__ inline float funmap(unsigned u) {
    unsigned v = (u & 0x80000000u) ? (u & 0x7fffffffu) : ~u;
    return __uint_as_float(v);
}

// ============================================================
// Wave-cooperative exact KNN: one wave per query.
// Distributed ascending top-list: lane i holds rank-i key
// (key = fmap(dist)<<32 | idx  -> exact (dist, idx) lex order,
//  matching top_k's smaller-index tie-break).
// Per 64-candidate batch: 1 dist/lane, ballot vs 25th-best
// threshold (lane 24); survivors inserted serially via
// shuffle-shift insertion with threshold re-filtering.
// Distances use _rn intrinsics to match numpy fp32 order
// (self-dist exactly 0). Lane 0 (global lex-min = self) dropped.
// ============================================================
__global__ __launch_bounds__(256) void knn_kernel(const float* __restrict__ xyz,
                                                  int* __restrict__ edges) {
    __shared__ float4 cand[1024];
    int b = blockIdx.y;
    int wave = threadIdx.x >> 6;
    int lane = threadIdx.x & 63;
    int n = blockIdx.x * 4 + wave;
    const float* xb = xyz + (size_t)b * 3 * 4096;

    float xq = xb[n], yq = xb[4096 + n], zq = xb[8192 + n];
    float sqq = __fadd_rn(__fadd_rn(__fmul_rn(xq, xq), __fmul_rn(yq, yq)), __fmul_rn(zq, zq));

    unsigned long long e = ~0ull;   // +inf sentinel key
    unsigned long long T = ~0ull;   // current 25th-best (lane 24)

    for (int strip = 0; strip < 4; ++strip) {
        __syncthreads();   // protect cand from previous strip's readers
        for (int i = threadIdx.x; i < 1024; i += 256) {
            int j = strip * 1024 + i;
            float x = xb[j], y = xb[4096 + j], z = xb[8192 + j];
            float sq = __fadd_rn(__fadd_rn(__fmul_rn(x, x), __fmul_rn(y, y)), __fmul_rn(z, z));
            cand[i] = make_float4(x, y, z, sq);
        }
        __syncthreads();

        for (int t = 0; t < 16; ++t) {
            float4 cv = cand[t * 64 + lane];
            float dot = __fadd_rn(__fadd_rn(__fmul_rn(xq, cv.x), __fmul_rn(yq, cv.y)), __fmul_rn(zq, cv.z));
            float d = __fsub_rn(__fadd_rn(sqq, cv.w), __fmul_rn(2.0f, dot));
            unsigned idx = (unsigned)(strip * 1024 + t * 64 + lane);
            unsigned long long key = ((unsigned long long)fmap(d) << 32) | idx;

            unsigned long long m = __ballot(key < T);
            while (m) {
                int l = __ffsll(m) - 1;
                unsigned long long kb = __shfl(key, l);
                unsigned long long sh = __shfl_up(e, 1);
                if (lane == 0) sh = 0ull;
                unsigned long long mx = (sh > kb) ? sh : kb;
                e = (e < mx) ? e : mx;
                T = __shfl(e, 24);
                m &= m - 1;
                if (m) m &= __ballot(key < T);
            }
        }
    }
    if (lane >= 1 && lane < 25)
        edges[((size_t)(b * 4096 + n)) * KNN + lane - 1] = (int)(unsigned)e;
}

// ============================================================
// a = pts·(W1-W2)^T ; c = pts·W2^T   (both [q][128], q = b*4096+n)
// ============================================================
__global__ __launch_bounds__(256) void feat_kernel(const float* __restrict__ pts,
                                                   const float* __restrict__ ec_w,
                                                   float* __restrict__ afeat,
                                                   float* __restrict__ cfeat) {
    __shared__ float inl[64 * 65];
    __shared__ float wa[64 * 132];
    __shared__ float wc[64 * 132];
    int n0 = blockIdx.x * 64;
    int b  = blockIdx.y;

    for (int idx = threadIdx.x; idx < 64 * 64; idx += 256) {
        int c = idx >> 6, p = idx & 63;
        inl[p * 65 + c] = pts[((size_t)(b * 64 + c) << 12) + n0 + p];
    }
    for (int idx = threadIdx.x; idx < 128 * 64; idx += 256) {
        int o = idx >> 6, cc = idx & 63;
        float w1 = ec_w[o * 128 + cc], w2 = ec_w[o * 128 + 64 + cc];
        wa[cc * 132 + o] = w1 - w2;
        wc[cc * 132 + o] = w2;
    }
    __syncthreads();

    int ng = threadIdx.x & 15, og = threadIdx.x >> 4;  // 16x16, OW=8
    float acca[4][8], accc[4][8];
    #pragma unroll
    for (int r = 0; r < 4; ++r)
        #pragma unroll
        for (int i = 0; i < 8; ++i) { acca[r][i] = 0.f; accc[r][i] = 0.f; }

    for (int c = 0; c < 64; ++c) {
        float pv[4];
        #pragma unroll
        for (int r = 0; r < 4; ++r) pv[r] = inl[(ng * 4 + r) * 65 + c];
        const float* wra = &wa[c * 132 + og * 8];
        const float* wrc = &wc[c * 132 + og * 8];
        float4 a0 = *(const float4*)&wra[0];
        float4 a1 = *(const float4*)&wra[4];
        float4 c0 = *(const float4*)&wrc[0];
        float4 c1 = *(const float4*)&wrc[4];
        float wva[8] = {a0.x, a0.y, a0.z, a0.w, a1.x, a1.y, a1.z, a1.w};
        float wvc[8] = {c0.x, c0.y, c0.z, c0.w, c1.x, c1.y, c1.z, c1.w};
        #pragma unroll
        for (int r = 0; r < 4; ++r)
            #pragma unroll
            for (int i = 0; i < 8; ++i) {
                acca[r][i] = fmaf(pv[r], wva[i], acca[r][i]);
                accc[r][i] = fmaf(pv[r], wvc[i], accc[r][i]);
            }
    }
    __syncthreads();
    float* outl = wa;  // reuse
    size_t base = (((size_t)b << 12) + n0) * 128;

    #pragma unroll
    for (int r = 0; r < 4; ++r)
        #pragma unroll
        for (int i = 0; i < 8; ++i)
            outl[(ng * 4 + r) * 132 + og * 8 + i] = acca[r][i];
    __syncthreads();
    for (int idx = threadIdx.x; idx < 64 * 128; idx += 256) {
        int p = idx >> 7, o = idx & 127;
        afeat[base + idx] = outl[p * 132 + o];
    }
    __syncthreads();
    #pragma unroll
    for (int r = 0; r < 4; ++r)
        #pragma unroll
        for (int i = 0; i < 8; ++i)
            outl[(ng * 4 + r) * 132 + og * 8 + i] = accc[r][i];
    __syncthreads();
    for (int idx = threadIdx.x; idx < 64 * 128; idx += 256) {
        int p = idx >> 7, o = idx & 127;
        cfeat[base + idx] = outl[p * 132 + o];
    }
}

// ============================================================
// Neighbor gather: M = a + max_k c[e_k]; BN1 stats from
// sum_k h = 24a+s, sum_k h^2 = 24a^2+2as+q.
// ============================================================
__global__ __launch_bounds__(256) void gather_stats_kernel(const float* __restrict__ afeat,
                                                           const float* __restrict__ cfeat,
                                                           const int* __restrict__ edges,
                                                           float* __restrict__ M,
                                                           float* __restrict__ st) {
    __shared__ int eL[16 * KNN];
    __shared__ float red[256];
    int q0 = blockIdx.x * 16;
    for (int idx = threadIdx.x; idx < 16 * KNN; idx += 256) eL[idx] = edges[(size_t)q0 * KNN + idx];
    __syncthreads();

    int o = threadIdx.x & 127, half = threadIdx.x >> 7;
    float s1 = 0.f, s2 = 0.f;
    for (int pi = 0; pi < 8; ++pi) {
        int p = half * 8 + pi;
        int q = q0 + p;
        int bbase = (q >> 12) << 12;
        float mx = -__builtin_inff(), sv = 0.f, qv = 0.f;
        #pragma unroll 4
        for (int k = 0; k < KNN; ++k) {
            int e = eL[p * KNN + k];
            float v = cfeat[((size_t)(bbase + e) << 7) + o];
            mx = fmaxf(mx, v);
            sv += v;
            qv = fmaf(v, v, qv);
        }
        float a = afeat[((size_t)q << 7) + o];
        M[((size_t)q << 7) + o] = a + mx;
        s1 += fmaf(24.f, a, sv);
        s2 += 24.f * a * a + 2.f * a * sv + qv;
    }
    red[threadIdx.x] = s1; __syncthreads();
    if (half == 0) atomicAdd(&st[o], red[o] + red[128 + o]);
    __syncthreads();
    red[threadIdx.x] = s2; __syncthreads();
    if (half == 0) atomicAdd(&st[128 + o], red[o] + red[128 + o]);
}

// ============================================================
// Generic layer: (optional BN+act on input) -> x·W^T (+bias) ->
// write raw output + accumulate per-channel (sum, sumsq) stats.
// MODE: 0 = concat(xyz,pts) input (no norm), 1 = relu norm-in,
//       2 = leaky norm-in.
// OSPLIT: output channels split across blockIdx.y for occupancy.
// Block: 64 points; thread tile: 4 points x OH/16 outputs.
// ============================================================
template<int I, int O, int OSPLIT, int MODE>
__global__ __launch_bounds__(256) void layer_kernel(
    const float* __restrict__ inraw, const float* __restrict__ inst, float rcnt,
    const float* __restrict__ ing, const float* __restrict__ inbe,
    const float* __restrict__ W, const float* __restrict__ bias,
    const float* __restrict__ xyz, const float* __restrict__ pts,
    float* __restrict__ outraw, float* __restrict__ outst)
{
    constexpr int OH = O / OSPLIT;            // outputs handled by this block
    constexpr int IP = (I & 1) ? I : I + 1;   // odd stride: conflict-friendly
    constexpr int OP = OH + 4;                // mult-of-4 stride: b128-aligned
    constexpr int OW = OH / 16;
    __shared__ float inl[64 * IP];
    __shared__ float wl[64 * OP];
    __shared__ float ns[I], nb[I];

    int q0 = blockIdx.x * 64;
    int o0 = blockIdx.y * OH;

    if (MODE != 0) {
        if (threadIdx.x < I) {
            int c = threadIdx.x;
            float m = inst[c] * rcnt;
            float v = inst[I + c] * rcnt - m * m;
            float inv = 1.0f / sqrtf(v + 1e-5f);
            float sc = inv * ing[c];
            ns[c] = sc;
            nb[c] = inbe[c] - m * sc;
        }
        __syncthreads();
        const float* src = inraw + (size_t)q0 * I;
        for (int idx = threadIdx.x; idx < 64 * I; idx += 256) {
            int p = idx / I, c = idx - p * I;
            float v = fmaf(src[idx], ns[c], nb[c]);
            if (MODE == 1) v = fmaxf(v, 0.0f);
            else           v = (v > 0.0f) ? v : 0.2f * v;
            inl[p * IP + c] = v;
        }
    } else {
        int b = q0 >> 12, n0 = q0 & 4095;
        for (int idx = threadIdx.x; idx < 64 * I; idx += 256) {
            int c = idx >> 6, p = idx & 63;
            float v;
            if (c < 3) v = xyz[((size_t)(b * 3 + c) << 12) + n0 + p];
            else       v = pts[((size_t)(b * 64 + (c - 3)) << 12) + n0 + p];
            inl[p * IP + c] = v;
        }
    }

    int ng = threadIdx.x & 15, og = threadIdx.x >> 4;
    float acc[4][OW];
    #pragma unroll
    for (int r = 0; r < 4; ++r)
        #pragma unroll
        for (int i = 0; i < OW; ++i) acc[r][i] = 0.f;

    for (int ct = 0; ct < I; ct += 64) {
        int CT = (I - ct < 64) ? (I - ct) : 64;
        __syncthreads();  // inl ready (iter 0) / previous wl consumed
        for (int idx = threadIdx.x; idx < CT * OH; idx += 256) {
            int o = idx / CT, cc = idx - o * CT;
            wl[cc * OP + o] = W[(size_t)(o0 + o) * I + ct + cc];
        }
        __syncthreads();
        for (int cc = 0; cc < CT; ++cc) {
            int c = ct + cc;
            float pv[4];
            #pragma unroll
            for (int r = 0; r < 4; ++r) pv[r] = inl[(ng * 4 + r) * IP + c];
            const float* wr = &wl[cc * OP + og * OW];
            #pragma unroll
            for (int i4 = 0; i4 < OW / 4; ++i4) {
                float4 wv = *(const float4*)&wr[i4 * 4];
                #pragma unroll
                for (int r = 0; r < 4; ++r) {
                    acc[r][i4 * 4 + 0] = fmaf(pv[r], wv.x, acc[r][i4 * 4 + 0]);
                    acc[r][i4 * 4 + 1] = fmaf(pv[r], wv.y, acc[r][i4 * 4 + 1]);
                    acc[r][i4 * 4 + 2] = fmaf(pv[r], wv.z, acc[r][i4 * 4 + 2]);
                    acc[r][i4 * 4 + 3] = fmaf(pv[r], wv.w, acc[r][i4 * 4 + 3]);
                }
            }
        }
    }

    if (bias != nullptr) {
        #pragma unroll
        for (int i = 0; i < OW; ++i) {
            float bv = bias[o0 + og * OW + i];
            #pragma unroll
            for (int r = 0; r < 4; ++r) acc[r][i] += bv;
        }
    }
    __syncthreads();
    // stage outputs (reuse wl) for coalesced store + stats
    #pragma unroll
    for (int r = 0; r < 4; ++r)
        #pragma unroll
        for (int i = 0; i < OW; ++i)
            wl[(ng * 4 + r) * OP + og * OW + i] = acc[r][i];
    __syncthreads();

    for (int idx = threadIdx.x; idx < 64 * OH; idx += 256) {
        int p = idx / OH, o = idx - p * OH;
        outraw[(size_t)(q0 + p) * O + o0 + o] = wl[p * OP + o];
    }
    if (threadIdx.x < OH) {
        int o = threadIdx.x;
        float s1 = 0.f, s2 = 0.f;
        #pragma unroll 8
        for (int p = 0; p < 64; ++p) {
            float v = wl[p * OP + o];
            s1 += v;
            s2 = fmaf(v, v, s2);
        }
        atomicAdd(&outst[o0 + o], s1);
        atomicAdd(&outst[O + o0 + o], s2);
    }
}

// ============================================================
// BN + activation + max over points -> atomicMax (mapped uint)
// ACT: 1 = relu, 0 = leaky
// ============================================================
template<int O, int ACT>
__global__ __launch_bounds__(256) void finalize_max_kernel(const float* __restrict__ raw,
                                                           const float* __restrict__ st, float rcnt,
                                                           const float* __restrict__ g,
                                                           const float* __restrict__ be,
                                                           unsigned* __restrict__ outmax) {
    constexpr int R = 256 / O;
    int b = blockIdx.y;
    int p0 = blockIdx.x * 256;
    int o = threadIdx.x & (O - 1);
    int rep = threadIdx.x / O;
    float m = st[o] * rcnt;
    float v = st[O + o] * rcnt - m * m;
    float inv = 1.0f / sqrtf(v + 1e-5f);
    float sc = inv * g[o];
    float sh = be[o] - m * sc;
    float mx = -__builtin_inff();
    for (int p = rep; p < 256; p += R) {
        float x = fmaf(raw[(size_t)(b * 4096 + p0 + p) * O + o], sc, sh);
        x = ACT ? fmaxf(x, 0.0f) : (x > 0.0f ? x : 0.2f * x);
        mx = fmaxf(mx, x);
    }
    atomicMax(&outmax[b * O + o], fmap(mx));
}

// ============================================================
// Final head: fused(384)·fu_w^T -> BN over B=4 -> leaky -> out
// ============================================================
__global__ __launch_bounds__(256) void final_kernel(const unsigned* __restrict__ pf,
                                                    const unsigned* __restrict__ gg,
                                                    const float* __restrict__ fu_w,
                                                    const float* __restrict__ fu_g,
                                                    const float* __restrict__ fu_b,
                                                    float* __restrict__ out) {
    __shared__ float fl[4 * 384];
    for (int idx = threadIdx.x; idx < 4 * 384; idx += 256) {
        int b = idx / 384, c = idx - b * 384;
        unsigned u = (c < 256) ? pf[b * 256 + c] : gg[b * 128 + (c - 256)];
        fl[idx] = funmap(u);
    }
    __syncthreads();
    int o = threadIdx.x;
    float f[4];
    #pragma unroll
    for (int b = 0; b < 4; ++b) {
        float acc = 0.f;
        for (int c = 0; c < 384; ++c) acc = fmaf(fl[b * 384 + c], fu_w[(size_t)o * 384 + c], acc);
        f[b] = acc;
    }
    float m = 0.25f * (f[0] + f[1] + f[2] + f[3]);
    float var = 0.f;
    #pragma unroll
    for (int b = 0; b < 4; ++b) { float t = f[b] - m; var = fmaf(t, t, var); }
    var *= 0.25f;
    float inv = 1.0f / sqrtf(var + 1e-5f);
    float gv = fu_g[o], bv = fu_b[o];
    #pragma unroll
    for (int b = 0; b < 4; ++b) {
        float x = (f[b] - m) * inv * gv + bv;
        x = (x > 0.0f) ? x : 0.2f * x;
        out[b * 256 + o] = x;
    }
}

extern "C" void kernel_launch(void* const* d_in, const int* in_sizes, int n_in,
                              void* d_out, int out_size, void* d_ws, size_t ws_size,
                              hipStream_t stream) {
    const float* xyz   = (const float*)d_in[0];
    const float* pts   = (const float*)d_in[1];
    const float* ec_w  = (const float*)d_in[2];
    const float* ec_g  = (const float*)d_in[3];
    const float* ec_b  = (const float*)d_in[4];
    const float* gm_w  = (const float*)d_in[5];
    const float* gm_g  = (const float*)d_in[6];
    const float* gm_b  = (const float*)d_in[7];
    const float* w0    = (const float*)d_in[8];
    const float* bias0 = (const float*)d_in[9];
    const float* g0    = (const float*)d_in[10];
    const float* be0   = (const float*)d_in[11];
    const float* w1    = (const float*)d_in[12];
    const float* bias1 = (const float*)d_in[13];
    const float* g1    = (const float*)d_in[14];
    const float* be1   = (const float*)d_in[15];
    const float* w2    = (const float*)d_in[16];
    const float* bias2 = (const float*)d_in[17];
    const float* g2    = (const float*)d_in[18];
    const float* be2   = (const float*)d_in[19];
    const float* fu_w  = (const float*)d_in[20];
    const float* fu_g  = (const float*)d_in[21];
    const float* fu_b  = (const float*)d_in[22];

    float* ws = (float*)d_ws;
    float* out = (float*)d_out;

    // zero stats + atomic-max buffers
    hipMemsetAsync(ws + ST_BASE, 0, ST_COUNT * sizeof(float), stream);

    // KNN (wave-cooperative, one kernel)
    knn_kernel<<<dim3(NPTS / 4, 4), 256, 0, stream>>>(xyz, (int*)(ws + OFF_EDGES));

    // edge-conv decomposition
    feat_kernel<<<dim3(64, 4), 256, 0, stream>>>(pts, ec_w, ws + OFF_A, ws + OFF_C);
    gather_stats_kernel<<<QN / 16, 256, 0, stream>>>(ws + OFF_A, ws + OFF_C, (int*)(ws + OFF_EDGES),
                                                     ws + OFF_M, ws + ST_BN1);

    // graph MLP: leaky(bn1(M)) @ gm_w^T -> gmraw + stats
    layer_kernel<128, 128, 2, 2><<<dim3(QN / 64, 2), 256, 0, stream>>>(
        ws + OFF_M, ws + ST_BN1, 1.0f / 393216.0f, ec_g, ec_b,
        gm_w, nullptr, nullptr, nullptr, ws + OFF_GM, ws + ST_GM);

    // point MLP
    layer_kernel<67, 64, 1, 0><<<dim3(QN / 64, 1), 256, 0, stream>>>(
        nullptr, nullptr, 0.f, nullptr, nullptr,
        w0, bias0, xyz, pts, ws + OFF_L0, ws + ST_L0);
    layer_kernel<64, 128, 2, 1><<<dim3(QN / 64, 2), 256, 0, stream>>>(
        ws + OFF_L0, ws + ST_L0, 1.0f / 16384.0f, g0, be0,
        w1, bias1, nullptr, nullptr, ws + OFF_L1, ws + ST_L1);
    layer_kernel<128, 256, 4, 1><<<dim3(QN / 64, 4), 256, 0, stream>>>(
        ws + OFF_L1, ws + ST_L1, 1.0f / 16384.0f, g1, be1,
        w2, bias2, nullptr, nullptr, ws + OFF_L2, ws + ST_L2);

    // reductions to per-batch features
    finalize_max_kernel<128, 0><<<dim3(16, 4), 256, 0, stream>>>(
        ws + OFF_GM, ws + ST_GM, 1.0f / 16384.0f, gm_g, gm_b, (unsigned*)(ws + OFF_GG));
    finalize_max_kernel<256, 1><<<dim3(16, 4), 256, 0, stream>>>(
        ws + OFF_L2, ws + ST_L2, 1.0f / 16384.0f, g2, be2, (unsigned*)(ws + OFF_PF));

    // fused head
    final_kernel<<<1, 256, 0, stream>>>((unsigned*)(ws + OFF_PF), (unsigned*)(ws + OFF_GG),
                                        fu_w, fu_g, fu_b, out);
}

// Round 3
// 451.974 us; speedup vs baseline: 2.8793x; 1.2463x over previous
//
#include <hip/hip_runtime.h>

// Problem constants
#define NPTS 4096
#define QN   16384      // B*N
#define KNN  24

// ---- workspace offsets (in float units) ----
static constexpr size_t OFF_EDGES = 0;                         // int[QN*24]
static constexpr size_t OFF_BIG   = 393216;
static constexpr size_t OFF_A     = OFF_BIG;                   // float[QN*128]
static constexpr size_t OFF_C     = OFF_BIG + 2097152;         // float[QN*128]
static constexpr size_t OFF_M     = OFF_BIG + 4194304;         // float[QN*128]
static constexpr size_t OFF_GM    = OFF_BIG + 6553600;         // float[QN*128]
static constexpr size_t OFF_L0    = OFF_GM + 2097152;          // float[QN*64]
static constexpr size_t OFF_L1    = OFF_L0 + 1048576;          // float[QN*128]
static constexpr size_t OFF_L2    = OFF_L1 + 2097152;          // float[QN*256]
static constexpr size_t ST_BASE   = OFF_L2 + 4194304;
static constexpr size_t ST_BN1    = ST_BASE;                   // 256 (sum, sumsq per 128 ch)
static constexpr size_t ST_GM     = ST_BASE + 256;             // 256
static constexpr size_t ST_L0     = ST_BASE + 512;             // 128
static constexpr size_t ST_L1     = ST_BASE + 640;             // 256
static constexpr size_t ST_L2     = ST_BASE + 896;             // 512
static constexpr size_t OFF_PF    = ST_BASE + 1408;            // 1024 uint (point_feat max)
static constexpr size_t OFF_GG    = ST_BASE + 2432;            // 512 uint (graph_glob max)
static constexpr size_t ST_COUNT  = 2944;                      // floats to zero

// order-preserving float<->uint map (handles possible tiny-negative dists)
__device__ inline unsigned fmap(float f) {
    unsigned u = __float_as_uint(f);
    return (u & 0x80000000u) ? ~u : (u | 0x80000000u);
}
__device__ inline float funmap(unsigned u) {
    unsigned v = (u & 0x80000000u) ? (u & 0x7fffffffu) : ~u;
    return __uint_as_float(v);
}

// ============================================================
// Wave-cooperative exact KNN, ballot-compaction formulation.
// One wave per query. Key = (fmap(dist)<<32)|idx -> exact
// (dist, idx) lexicographic order == top_k tie-breaking.
// Stream 64 cands/batch: 1 cmp + ballot vs wave-uniform T
// (= current 25th-best dist bits). Survivors compact-write
// their key into an LDS buffer (mbcnt prefix, ds_write_b64).
// When buffer >= 64: rank-count reduce (broadcast LDS reads,
// u64 compares) keeps sorted top-25 in place, tightens T.
// No serial per-element shuffle chains anywhere.
// Distances use _rn intrinsics to match numpy fp32 order
// (self-dist exactly 0). Rank 0 (global lex-min = self) dropped.
// ============================================================
__global__ __launch_bounds__(256) void knn_kernel(const float* __restrict__ xyz,
                                                  int* __restrict__ edges) {
    __shared__ float4 cand[1024];
    __shared__ unsigned long long buf[4][128];
    int b = blockIdx.y;
    int wave = threadIdx.x >> 6;
    int lane = threadIdx.x & 63;
    int n = blockIdx.x * 4 + wave;
    const float* xb = xyz + (size_t)b * 3 * 4096;
    unsigned long long* wbuf = buf[wave];

    float xq = xb[n], yq = xb[4096 + n], zq = xb[8192 + n];
    float sqq = __fadd_rn(__fadd_rn(__fmul_rn(xq, xq), __fmul_rn(yq, yq)), __fmul_rn(zq, zq));

    unsigned T = 0xFFFFFFFFu;  // current 25th-best dist bits (admit-all at start)
    int count = 0;             // wave-uniform buffer fill

    // rank-count reduce: sort buffered keys, keep top-25, tighten T
    auto reduce = [&]() {
        unsigned long long ka = (lane < count) ? wbuf[lane] : ~0ull;
        int ra = 0;
        if (count > 64) {
            unsigned long long kb = (lane + 64 < count) ? wbuf[lane + 64] : ~0ull;
            int rb = 0;
            for (int j = 0; j < count; ++j) {
                unsigned long long kj = wbuf[j];
                ra += (kj < ka);
                rb += (kj < kb);
            }
            if (rb < 25) wbuf[rb] = kb;   // wave-lockstep: loop reads complete first
        } else {
            for (int j = 0; j < count; ++j) {
                unsigned long long kj = wbuf[j];
                ra += (kj < ka);
            }
        }
        if (ra < 25) wbuf[ra] = ka;
        count = 25;
        T = (unsigned)(wbuf[24] >> 32);
    };

    for (int strip = 0; strip < 4; ++strip) {
        __syncthreads();   // protect cand from previous strip's readers
        for (int i = threadIdx.x; i < 1024; i += 256) {
            int j = strip * 1024 + i;
            float x = xb[j], y = xb[4096 + j], z = xb[8192 + j];
            float sq = __fadd_rn(__fadd_rn(__fmul_rn(x, x), __fmul_rn(y, y)), __fmul_rn(z, z));
            cand[i] = make_float4(x, y, z, sq);
        }
        __syncthreads();

        for (int t = 0; t < 16; ++t) {
            float4 cv = cand[t * 64 + lane];
            float dot = __fadd_rn(__fadd_rn(__fmul_rn(xq, cv.x), __fmul_rn(yq, cv.y)), __fmul_rn(zq, cv.z));
            float d = __fsub_rn(__fadd_rn(sqq, cv.w), __fmul_rn(2.0f, dot));
            unsigned du = fmap(d);
            bool surv = (du <= T);
            unsigned long long m = __ballot(surv);
            if (m) {
                if (surv) {
                    int ofs = __popcll(m & ((1ull << lane) - 1ull));
                    unsigned idx = (unsigned)(strip * 1024 + t * 64 + lane);
                    wbuf[count + ofs] = ((unsigned long long)du << 32) | idx;
                }
                count += (int)__popcll(m);
                if (count >= 64) reduce();
            }
        }
    }
    reduce();  // final: buffer sorted ascending by (dist, idx)
    if (lane >= 1 && lane < 25)
        edges[((size_t)(b * 4096 + n)) * KNN + lane - 1] = (int)(unsigned)(wbuf[lane] & 0xFFFFFFFFull);
}

// ============================================================
// a = pts·(W1-W2)^T ; c = pts·W2^T   (both [q][128], q = b*4096+n)
// ============================================================
__global__ __launch_bounds__(256) void feat_kernel(const float* __restrict__ pts,
                                                   const float* __restrict__ ec_w,
                                                   float* __restrict__ afeat,
                                                   float* __restrict__ cfeat) {
    __shared__ float inl[64 * 65];
    __shared__ float wa[64 * 132];
    __shared__ float wc[64 * 132];
    int n0 = blockIdx.x * 64;
    int b  = blockIdx.y;

    for (int idx = threadIdx.x; idx < 64 * 64; idx += 256) {
        int c = idx >> 6, p = idx & 63;
        inl[p * 65 + c] = pts[((size_t)(b * 64 + c) << 12) + n0 + p];
    }
    for (int idx = threadIdx.x; idx < 128 * 64; idx += 256) {
        int o = idx >> 6, cc = idx & 63;
        float w1 = ec_w[o * 128 + cc], w2 = ec_w[o * 128 + 64 + cc];
        wa[cc * 132 + o] = w1 - w2;
        wc[cc * 132 + o] = w2;
    }
    __syncthreads();

    int ng = threadIdx.x & 15, og = threadIdx.x >> 4;  // 16x16, OW=8
    float acca[4][8], accc[4][8];
    #pragma unroll
    for (int r = 0; r < 4; ++r)
        #pragma unroll
        for (int i = 0; i < 8; ++i) { acca[r][i] = 0.f; accc[r][i] = 0.f; }

    for (int c = 0; c < 64; ++c) {
        float pv[4];
        #pragma unroll
        for (int r = 0; r < 4; ++r) pv[r] = inl[(ng * 4 + r) * 65 + c];
        const float* wra = &wa[c * 132 + og * 8];
        const float* wrc = &wc[c * 132 + og * 8];
        float4 a0 = *(const float4*)&wra[0];
        float4 a1 = *(const float4*)&wra[4];
        float4 c0 = *(const float4*)&wrc[0];
        float4 c1 = *(const float4*)&wrc[4];
        float wva[8] = {a0.x, a0.y, a0.z, a0.w, a1.x, a1.y, a1.z, a1.w};
        float wvc[8] = {c0.x, c0.y, c0.z, c0.w, c1.x, c1.y, c1.z, c1.w};
        #pragma unroll
        for (int r = 0; r < 4; ++r)
            #pragma unroll
            for (int i = 0; i < 8; ++i) {
                acca[r][i] = fmaf(pv[r], wva[i], acca[r][i]);
                accc[r][i] = fmaf(pv[r], wvc[i], accc[r][i]);
            }
    }
    __syncthreads();
    float* outl = wa;  // reuse
    size_t base = (((size_t)b << 12) + n0) * 128;

    #pragma unroll
    for (int r = 0; r < 4; ++r)
        #pragma unroll
        for (int i = 0; i < 8; ++i)
            outl[(ng * 4 + r) * 132 + og * 8 + i] = acca[r][i];
    __syncthreads();
    for (int idx = threadIdx.x; idx < 64 * 128; idx += 256) {
        int p = idx >> 7, o = idx & 127;
        afeat[base + idx] = outl[p * 132 + o];
    }
    __syncthreads();
    #pragma unroll
    for (int r = 0; r < 4; ++r)
        #pragma unroll
        for (int i = 0; i < 8; ++i)
            outl[(ng * 4 + r) * 132 + og * 8 + i] = accc[r][i];
    __syncthreads();
    for (int idx = threadIdx.x; idx < 64 * 128; idx += 256) {
        int p = idx >> 7, o = idx & 127;
        cfeat[base + idx] = outl[p * 132 + o];
    }
}

// ============================================================
// Neighbor gather: M = a + max_k c[e_k]; BN1 stats from
// sum_k h = 24a+s, sum_k h^2 = 24a^2+2as+q.
// ============================================================
__global__ __launch_bounds__(256) void gather_stats_kernel(const float* __restrict__ afeat,
                                                           const float* __restrict__ cfeat,
                                                           const int* __restrict__ edges,
                                                           float* __restrict__ M,
                                                           float* __restrict__ st) {
    __shared__ int eL[16 * KNN];
    __shared__ float red[256];
    int q0 = blockIdx.x * 16;
    for (int idx = threadIdx.x; idx < 16 * KNN; idx += 256) eL[idx] = edges[(size_t)q0 * KNN + idx];
    __syncthreads();

    int o = threadIdx.x & 127, half = threadIdx.x >> 7;
    float s1 = 0.f, s2 = 0.f;
    for (int pi = 0; pi < 8; ++pi) {
        int p = half * 8 + pi;
        int q = q0 + p;
        int bbase = (q >> 12) << 12;
        float mx = -__builtin_inff(), sv = 0.f, qv = 0.f;
        #pragma unroll 4
        for (int k = 0; k < KNN; ++k) {
            int e = eL[p * KNN + k];
            float v = cfeat[((size_t)(bbase + e) << 7) + o];
            mx = fmaxf(mx, v);
            sv += v;
            qv = fmaf(v, v, qv);
        }
        float a = afeat[((size_t)q << 7) + o];
        M[((size_t)q << 7) + o] = a + mx;
        s1 += fmaf(24.f, a, sv);
        s2 += 24.f * a * a + 2.f * a * sv + qv;
    }
    red[threadIdx.x] = s1; __syncthreads();
    if (half == 0) atomicAdd(&st[o], red[o] + red[128 + o]);
    __syncthreads();
    red[threadIdx.x] = s2; __syncthreads();
    if (half == 0) atomicAdd(&st[128 + o], red[o] + red[128 + o]);
}

// ============================================================
// Generic layer: (optional BN+act on input) -> x·W^T (+bias) ->
// write raw output + accumulate per-channel (sum, sumsq) stats.
// MODE: 0 = concat(xyz,pts) input (no norm), 1 = relu norm-in,
//       2 = leaky norm-in.
// OSPLIT: output channels split across blockIdx.y for occupancy.
// Block: 64 points; thread tile: 4 points x OH/16 outputs.
// ============================================================
template<int I, int O, int OSPLIT, int MODE>
__global__ __launch_bounds__(256) void layer_kernel(
    const float* __restrict__ inraw, const float* __restrict__ inst, float rcnt,
    const float* __restrict__ ing, const float* __restrict__ inbe,
    const float* __restrict__ W, const float* __restrict__ bias,
    const float* __restrict__ xyz, const float* __restrict__ pts,
    float* __restrict__ outraw, float* __restrict__ outst)
{
    constexpr int OH = O / OSPLIT;            // outputs handled by this block
    constexpr int IP = (I & 1) ? I : I + 1;   // odd stride: conflict-friendly
    constexpr int OP = OH + 4;                // mult-of-4 stride: b128-aligned
    constexpr int OW = OH / 16;
    __shared__ float inl[64 * IP];
    __shared__ float wl[64 * OP];
    __shared__ float ns[I], nb[I];

    int q0 = blockIdx.x * 64;
    int o0 = blockIdx.y * OH;

    if (MODE != 0) {
        if (threadIdx.x < I) {
            int c = threadIdx.x;
            float m = inst[c] * rcnt;
            float v = inst[I + c] * rcnt - m * m;
            float inv = 1.0f / sqrtf(v + 1e-5f);
            float sc = inv * ing[c];
            ns[c] = sc;
            nb[c] = inbe[c] - m * sc;
        }
        __syncthreads();
        const float* src = inraw + (size_t)q0 * I;
        for (int idx = threadIdx.x; idx < 64 * I; idx += 256) {
            int p = idx / I, c = idx - p * I;
            float v = fmaf(src[idx], ns[c], nb[c]);
            if (MODE == 1) v = fmaxf(v, 0.0f);
            else           v = (v > 0.0f) ? v : 0.2f * v;
            inl[p * IP + c] = v;
        }
    } else {
        int b = q0 >> 12, n0 = q0 & 4095;
        for (int idx = threadIdx.x; idx < 64 * I; idx += 256) {
            int c = idx >> 6, p = idx & 63;
            float v;
            if (c < 3) v = xyz[((size_t)(b * 3 + c) << 12) + n0 + p];
            else       v = pts[((size_t)(b * 64 + (c - 3)) << 12) + n0 + p];
            inl[p * IP + c] = v;
        }
    }

    int ng = threadIdx.x & 15, og = threadIdx.x >> 4;
    float acc[4][OW];
    #pragma unroll
    for (int r = 0; r < 4; ++r)
        #pragma unroll
        for (int i = 0; i < OW; ++i) acc[r][i] = 0.f;

    for (int ct = 0; ct < I; ct += 64) {
        int CT = (I - ct < 64) ? (I - ct) : 64;
        __syncthreads();  // inl ready (iter 0) / previous wl consumed
        for (int idx = threadIdx.x; idx < CT * OH; idx += 256) {
            int o = idx / CT, cc = idx - o * CT;
            wl[cc * OP + o] = W[(size_t)(o0 + o) * I + ct + cc];
        }
        __syncthreads();
        for (int cc = 0; cc < CT; ++cc) {
            int c = ct + cc;
            float pv[4];
            #pragma unroll
            for (int r = 0; r < 4; ++r) pv[r] = inl[(ng * 4 + r) * IP + c];
            const float* wr = &wl[cc * OP + og * OW];
            #pragma unroll
            for (int i4 = 0; i4 < OW / 4; ++i4) {
                float4 wv = *(const float4*)&wr[i4 * 4];
                #pragma unroll
                for (int r = 0; r < 4; ++r) {
                    acc[r][i4 * 4 + 0] = fmaf(pv[r], wv.x, acc[r][i4 * 4 + 0]);
                    acc[r][i4 * 4 + 1] = fmaf(pv[r], wv.y, acc[r][i4 * 4 + 1]);
                    acc[r][i4 * 4 + 2] = fmaf(pv[r], wv.z, acc[r][i4 * 4 + 2]);
                    acc[r][i4 * 4 + 3] = fmaf(pv[r], wv.w, acc[r][i4 * 4 + 3]);
                }
            }
        }
    }

    if (bias != nullptr) {
        #pragma unroll
        for (int i = 0; i < OW; ++i) {
            float bv = bias[o0 + og * OW + i];
            #pragma unroll
            for (int r = 0; r < 4; ++r) acc[r][i] += bv;
        }
    }
    __syncthreads();
    // stage outputs (reuse wl) for coalesced store + stats
    #pragma unroll
    for (int r = 0; r < 4; ++r)
        #pragma unroll
        for (int i = 0; i < OW; ++i)
            wl[(ng * 4 + r) * OP + og * OW + i] = acc[r][i];
    __syncthreads();

    for (int idx = threadIdx.x; idx < 64 * OH; idx += 256) {
        int p = idx / OH, o = idx - p * OH;
        outraw[(size_t)(q0 + p) * O + o0 + o] = wl[p * OP + o];
    }
    if (threadIdx.x < OH) {
        int o = threadIdx.x;
        float s1 = 0.f, s2 = 0.f;
        #pragma unroll 8
        for (int p = 0; p < 64; ++p) {
            float v = wl[p * OP + o];
            s1 += v;
            s2 = fmaf(v, v, s2);
        }
        atomicAdd(&outst[o0 + o], s1);
        atomicAdd(&outst[O + o0 + o], s2);
    }
}

// ============================================================
// BN + activation + max over points -> atomicMax (mapped uint)
// ACT: 1 = relu, 0 = leaky
// ============================================================
template<int O, int ACT>
__global__ __launch_bounds__(256) void finalize_max_kernel(const float* __restrict__ raw,
                                                           const float* __restrict__ st, float rcnt,
                                                           const float* __restrict__ g,
                                                           const float* __restrict__ be,
                                                           unsigned* __restrict__ outmax) {
    constexpr int R = 256 / O;
    int b = blockIdx.y;
    int p0 = blockIdx.x * 256;
    int o = threadIdx.x & (O - 1);
    int rep = threadIdx.x / O;
    float m = st[o] * rcnt;
    float v = st[O + o] * rcnt - m * m;
    float inv = 1.0f / sqrtf(v + 1e-5f);
    float sc = inv * g[o];
    float sh = be[o] - m * sc;
    float mx = -__builtin_inff();
    for (int p = rep; p < 256; p += R) {
        float x = fmaf(raw[(size_t)(b * 4096 + p0 + p) * O + o], sc, sh);
        x = ACT ? fmaxf(x, 0.0f) : (x > 0.0f ? x : 0.2f * x);
        mx = fmaxf(mx, x);
    }
    atomicMax(&outmax[b * O + o], fmap(mx));
}

// ============================================================
// Final head: fused(384)·fu_w^T -> BN over B=4 -> leaky -> out
// ============================================================
__global__ __launch_bounds__(256) void final_kernel(const unsigned* __restrict__ pf,
                                                    const unsigned* __restrict__ gg,
                                                    const float* __restrict__ fu_w,
                                                    const float* __restrict__ fu_g,
                                                    const float* __restrict__ fu_b,
                                                    float* __restrict__ out) {
    __shared__ float fl[4 * 384];
    for (int idx = threadIdx.x; idx < 4 * 384; idx += 256) {
        int b = idx / 384, c = idx - b * 384;
        unsigned u = (c < 256) ? pf[b * 256 + c] : gg[b * 128 + (c - 256)];
        fl[idx] = funmap(u);
    }
    __syncthreads();
    int o = threadIdx.x;
    float f[4];
    #pragma unroll
    for (int b = 0; b < 4; ++b) {
        float acc = 0.f;
        for (int c = 0; c < 384; ++c) acc = fmaf(fl[b * 384 + c], fu_w[(size_t)o * 384 + c], acc);
        f[b] = acc;
    }
    float m = 0.25f * (f[0] + f[1] + f[2] + f[3]);
    float var = 0.f;
    #pragma unroll
    for (int b = 0; b < 4; ++b) { float t = f[b] - m; var = fmaf(t, t, var); }
    var *= 0.25f;
    float inv = 1.0f / sqrtf(var + 1e-5f);
    float gv = fu_g[o], bv = fu_b[o];
    #pragma unroll
    for (int b = 0; b < 4; ++b) {
        float x = (f[b] - m) * inv * gv + bv;
        x = (x > 0.0f) ? x : 0.2f * x;
        out[b * 256 + o] = x;
    }
}

extern "C" void kernel_launch(void* const* d_in, const int* in_sizes, int n_in,
                              void* d_out, int out_size, void* d_ws, size_t ws_size,
                              hipStream_t stream) {
    const float* xyz   = (const float*)d_in[0];
    const float* pts   = (const float*)d_in[1];
    const float* ec_w  = (const float*)d_in[2];
    const float* ec_g  = (const float*)d_in[3];
    const float* ec_b  = (const float*)d_in[4];
    const float* gm_w  = (const float*)d_in[5];
    const float* gm_g  = (const float*)d_in[6];
    const float* gm_b  = (const float*)d_in[7];
    const float* w0    = (const float*)d_in[8];
    const float* bias0 = (const float*)d_in[9];
    const float* g0    = (const float*)d_in[10];
    const float* be0   = (const float*)d_in[11];
    const float* w1    = (const float*)d_in[12];
    const float* bias1 = (const float*)d_in[13];
    const float* g1    = (const float*)d_in[14];
    const float* be1   = (const float*)d_in[15];
    const float* w2    = (const float*)d_in[16];
    const float* bias2 = (const float*)d_in[17];
    const float* g2    = (const float*)d_in[18];
    const float* be2   = (const float*)d_in[19];
    const float* fu_w  = (const float*)d_in[20];
    const float* fu_g  = (const float*)d_in[21];
    const float* fu_b  = (const float*)d_in[22];

    float* ws = (float*)d_ws;
    float* out = (float*)d_out;

    // zero stats + atomic-max buffers
    hipMemsetAsync(ws + ST_BASE, 0, ST_COUNT * sizeof(float), stream);

    // KNN (wave-cooperative, ballot-compaction)
    knn_kernel<<<dim3(NPTS / 4, 4), 256, 0, stream>>>(xyz, (int*)(ws + OFF_EDGES));

    // edge-conv decomposition
    feat_kernel<<<dim3(64, 4), 256, 0, stream>>>(pts, ec_w, ws + OFF_A, ws + OFF_C);
    gather_stats_kernel<<<QN / 16, 256, 0, stream>>>(ws + OFF_A, ws + OFF_C, (int*)(ws + OFF_EDGES),
                                                     ws + OFF_M, ws + ST_BN1);

    // graph MLP: leaky(bn1(M)) @ gm_w^T -> gmraw + stats
    layer_kernel<128, 128, 2, 2><<<dim3(QN / 64, 2), 256, 0, stream>>>(
        ws + OFF_M, ws + ST_BN1, 1.0f / 393216.0f, ec_g, ec_b,
        gm_w, nullptr, nullptr, nullptr, ws + OFF_GM, ws + ST_GM);

    // point MLP
    layer_kernel<67, 64, 1, 0><<<dim3(QN / 64, 1), 256, 0, stream>>>(
        nullptr, nullptr, 0.f, nullptr, nullptr,
        w0, bias0, xyz, pts, ws + OFF_L0, ws + ST_L0);
    layer_kernel<64, 128, 2, 1><<<dim3(QN / 64, 2), 256, 0, stream>>>(
        ws + OFF_L0, ws + ST_L0, 1.0f / 16384.0f, g0, be0,
        w1, bias1, nullptr, nullptr, ws + OFF_L1, ws + ST_L1);
    layer_kernel<128, 256, 4, 1><<<dim3(QN / 64, 4), 256, 0, stream>>>(
        ws + OFF_L1, ws + ST_L1, 1.0f / 16384.0f, g1, be1,
        w2, bias2, nullptr, nullptr, ws + OFF_L2, ws + ST_L2);

    // reductions to per-batch features
    finalize_max_kernel<128, 0><<<dim3(16, 4), 256, 0, stream>>>(
        ws + OFF_GM, ws + ST_GM, 1.0f / 16384.0f, gm_g, gm_b, (unsigned*)(ws + OFF_GG));
    finalize_max_kernel<256, 1><<<dim3(16, 4), 256, 0, stream>>>(
        ws + OFF_L2, ws + ST_L2, 1.0f / 16384.0f, g2, be2, (unsigned*)(ws + OFF_PF));

    // fused head
    final_kernel<<<1, 256, 0, stream>>>((unsigned*)(ws + OFF_PF), (unsigned*)(ws + OFF_GG),
                                        fu_w, fu_g, fu_b, out);
}

// Round 4
// 396.335 us; speedup vs baseline: 3.2835x; 1.1404x over previous
//
#include <hip/hip_runtime.h>

// Problem constants
#define NPTS 4096
#define QN   16384      // B*N
#define KNN  24

// ---- workspace offsets (in float units) ----
static constexpr size_t OFF_EDGES = 0;                         // int[QN*24]
static constexpr size_t OFF_BIG   = 393216;
static constexpr size_t OFF_A     = OFF_BIG;                   // float[QN*128]
static constexpr size_t OFF_C     = OFF_BIG + 2097152;         // float[QN*128]
static constexpr size_t OFF_M     = OFF_BIG + 4194304;         // float[QN*128]
static constexpr size_t OFF_GM    = OFF_BIG + 6553600;         // float[QN*128]
static constexpr size_t OFF_L0    = OFF_GM + 2097152;          // float[QN*64]
static constexpr size_t OFF_L1    = OFF_L0 + 1048576;          // float[QN*128]
static constexpr size_t OFF_L2    = OFF_L1 + 2097152;          // float[QN*256]
static constexpr size_t ST_BASE   = OFF_L2 + 4194304;
static constexpr size_t ST_BN1    = ST_BASE;                   // 256 (sum, sumsq per 128 ch)
static constexpr size_t ST_GM     = ST_BASE + 256;             // 256
static constexpr size_t ST_L0     = ST_BASE + 512;             // 128
static constexpr size_t ST_L1     = ST_BASE + 640;             // 256
static constexpr size_t ST_L2     = ST_BASE + 896;             // 512
static constexpr size_t OFF_PF    = ST_BASE + 1408;            // 1024 uint (point_feat max)
static constexpr size_t OFF_GG    = ST_BASE + 2432;            // 512 uint (graph_glob max)
static constexpr size_t ST_COUNT  = 2944;                      // floats to zero

// order-preserving float<->uint map (handles possible tiny-negative dists)
__device__ inline unsigned fmap(float f) {
    unsigned u = __float_as_uint(f);
    return (u & 0x80000000u) ? ~u : (u | 0x80000000u);
}
__device__ inline float funmap(unsigned u) {
    unsigned v = (u & 0x80000000u) ? (u & 0x7fffffffu) : ~u;
    return __uint_as_float(v);
}

// XCD-affinity swizzle (XCD = flat block id % 8 heuristic): batch b owns
// XCD pair {2b, 2b+1}. Bijection on [0, 8*CH): bid -> (b, chunk).
// b = (bid&7)>>1, chunk = 2*(bid>>3) + (bid&1).
__device__ inline void xcd_map(int bid, int& b, int& chunk) {
    b = (bid & 7) >> 1;
    chunk = ((bid >> 3) << 1) | (bid & 1);
}

// ============================================================
// Wave-cooperative exact KNN, ballot-compaction formulation.
// (unchanged from R3 — control kernel, ~82 us, VALU-bound)
// ============================================================
__global__ __launch_bounds__(256) void knn_kernel(const float* __restrict__ xyz,
                                                  int* __restrict__ edges) {
    __shared__ float4 cand[1024];
    __shared__ unsigned long long buf[4][128];
    int b = blockIdx.y;
    int wave = threadIdx.x >> 6;
    int lane = threadIdx.x & 63;
    int n = blockIdx.x * 4 + wave;
    const float* xb = xyz + (size_t)b * 3 * 4096;
    unsigned long long* wbuf = buf[wave];

    float xq = xb[n], yq = xb[4096 + n], zq = xb[8192 + n];
    float sqq = __fadd_rn(__fadd_rn(__fmul_rn(xq, xq), __fmul_rn(yq, yq)), __fmul_rn(zq, zq));

    unsigned T = 0xFFFFFFFFu;
    int count = 0;

    auto reduce = [&]() {
        unsigned long long ka = (lane < count) ? wbuf[lane] : ~0ull;
        int ra = 0;
        if (count > 64) {
            unsigned long long kb = (lane + 64 < count) ? wbuf[lane + 64] : ~0ull;
            int rb = 0;
            for (int j = 0; j < count; ++j) {
                unsigned long long kj = wbuf[j];
                ra += (kj < ka);
                rb += (kj < kb);
            }
            if (rb < 25) wbuf[rb] = kb;
        } else {
            for (int j = 0; j < count; ++j) {
                unsigned long long kj = wbuf[j];
                ra += (kj < ka);
            }
        }
        if (ra < 25) wbuf[ra] = ka;
        count = 25;
        T = (unsigned)(wbuf[24] >> 32);
    };

    for (int strip = 0; strip < 4; ++strip) {
        __syncthreads();
        for (int i = threadIdx.x; i < 1024; i += 256) {
            int j = strip * 1024 + i;
            float x = xb[j], y = xb[4096 + j], z = xb[8192 + j];
            float sq = __fadd_rn(__fadd_rn(__fmul_rn(x, x), __fmul_rn(y, y)), __fmul_rn(z, z));
            cand[i] = make_float4(x, y, z, sq);
        }
        __syncthreads();

        for (int t = 0; t < 16; ++t) {
            float4 cv = cand[t * 64 + lane];
            float dot = __fadd_rn(__fadd_rn(__fmul_rn(xq, cv.x), __fmul_rn(yq, cv.y)), __fmul_rn(zq, cv.z));
            float d = __fsub_rn(__fadd_rn(sqq, cv.w), __fmul_rn(2.0f, dot));
            unsigned du = fmap(d);
            bool surv = (du <= T);
            unsigned long long m = __ballot(surv);
            if (m) {
                if (surv) {
                    int ofs = __popcll(m & ((1ull << lane) - 1ull));
                    unsigned idx = (unsigned)(strip * 1024 + t * 64 + lane);
                    wbuf[count + ofs] = ((unsigned long long)du << 32) | idx;
                }
                count += (int)__popcll(m);
                if (count >= 64) reduce();
            }
        }
    }
    reduce();
    if (lane >= 1 && lane < 25)
        edges[((size_t)(b * 4096 + n)) * KNN + lane - 1] = (int)(unsigned)(wbuf[lane] & 0xFFFFFFFFull);
}

// ============================================================
// a = pts·(W1-W2)^T ; c = pts·W2^T   (both [q][128])
// 1-D grid 256 with XCD-affinity mapping (batch -> XCD pair).
// ============================================================
__global__ __launch_bounds__(256) void feat_kernel(const float* __restrict__ pts,
                                                   const float* __restrict__ ec_w,
                                                   float* __restrict__ afeat,
                                                   float* __restrict__ cfeat) {
    __shared__ float inl[64 * 65];
    __shared__ float wa[64 * 132];
    __shared__ float wc[64 * 132];
    int b, chunk;
    xcd_map(blockIdx.x, b, chunk);
    int n0 = chunk * 64;

    for (int idx = threadIdx.x; idx < 64 * 64; idx += 256) {
        int c = idx >> 6, p = idx & 63;
        inl[p * 65 + c] = pts[((size_t)(b * 64 + c) << 12) + n0 + p];
    }
    for (int idx = threadIdx.x; idx < 128 * 64; idx += 256) {
        int o = idx >> 6, cc = idx & 63;
        float w1 = ec_w[o * 128 + cc], w2 = ec_w[o * 128 + 64 + cc];
        wa[cc * 132 + o] = w1 - w2;
        wc[cc * 132 + o] = w2;
    }
    __syncthreads();

    int ng = threadIdx.x & 15, og = threadIdx.x >> 4;  // 16x16, OW=8
    float acca[4][8], accc[4][8];
    #pragma unroll
    for (int r = 0; r < 4; ++r)
        #pragma unroll
        for (int i = 0; i < 8; ++i) { acca[r][i] = 0.f; accc[r][i] = 0.f; }

    for (int c = 0; c < 64; ++c) {
        float pv[4];
        #pragma unroll
        for (int r = 0; r < 4; ++r) pv[r] = inl[(ng * 4 + r) * 65 + c];
        const float* wra = &wa[c * 132 + og * 8];
        const float* wrc = &wc[c * 132 + og * 8];
        float4 a0 = *(const float4*)&wra[0];
        float4 a1 = *(const float4*)&wra[4];
        float4 c0 = *(const float4*)&wrc[0];
        float4 c1 = *(const float4*)&wrc[4];
        float wva[8] = {a0.x, a0.y, a0.z, a0.w, a1.x, a1.y, a1.z, a1.w};
        float wvc[8] = {c0.x, c0.y, c0.z, c0.w, c1.x, c1.y, c1.z, c1.w};
        #pragma unroll
        for (int r = 0; r < 4; ++r)
            #pragma unroll
            for (int i = 0; i < 8; ++i) {
                acca[r][i] = fmaf(pv[r], wva[i], acca[r][i]);
                accc[r][i] = fmaf(pv[r], wvc[i], accc[r][i]);
            }
    }
    __syncthreads();
    float* outl = wa;  // reuse
    size_t base = (((size_t)b << 12) + n0) * 128;

    #pragma unroll
    for (int r = 0; r < 4; ++r)
        #pragma unroll
        for (int i = 0; i < 8; ++i)
            outl[(ng * 4 + r) * 132 + og * 8 + i] = acca[r][i];
    __syncthreads();
    for (int idx = threadIdx.x; idx < 64 * 128; idx += 256) {
        int p = idx >> 7, o = idx & 127;
        afeat[base + idx] = outl[p * 132 + o];
    }
    __syncthreads();
    #pragma unroll
    for (int r = 0; r < 4; ++r)
        #pragma unroll
        for (int i = 0; i < 8; ++i)
            outl[(ng * 4 + r) * 132 + og * 8 + i] = accc[r][i];
    __syncthreads();
    for (int idx = threadIdx.x; idx < 64 * 128; idx += 256) {
        int p = idx >> 7, o = idx & 127;
        cfeat[base + idx] = outl[p * 132 + o];
    }
}

// ============================================================
// Neighbor gather: M = a + max_k c[e_k]; BN1 stats via
// sum_k h = 24a+s, sum_k h^2 = 24a^2+2as+q.
// float4 per thread (4 channels), 8 point-groups x 2 points.
// XCD-affinity: batch -> XCD pair (cfeat L2-resident).
// ============================================================
__global__ __launch_bounds__(256) void gather_stats_kernel(const float* __restrict__ afeat,
                                                           const float* __restrict__ cfeat,
                                                           const int* __restrict__ edges,
                                                           float* __restrict__ M,
                                                           float* __restrict__ st) {
    __shared__ int eL[16 * KNN];
    __shared__ float red[8][132];
    int b, chunk;
    xcd_map(blockIdx.x, b, chunk);     // chunk in [0,256)
    int q0 = b * 4096 + chunk * 16;
    for (int idx = threadIdx.x; idx < 16 * KNN; idx += 256) eL[idx] = edges[(size_t)q0 * KNN + idx];
    __syncthreads();

    int m = threadIdx.x & 31;   // channel quad: ch = 4m..4m+3
    int g = threadIdx.x >> 5;   // point group
    int bbase = b << 12;
    float s1[4] = {0.f, 0.f, 0.f, 0.f}, s2[4] = {0.f, 0.f, 0.f, 0.f};

    #pragma unroll
    for (int half = 0; half < 2; ++half) {
        int p = g + half * 8;
        int q = q0 + p;
        float mx0 = -__builtin_inff(), mx1 = mx0, mx2 = mx0, mx3 = mx0;
        float sv0 = 0.f, sv1 = 0.f, sv2 = 0.f, sv3 = 0.f;
        float qv0 = 0.f, qv1 = 0.f, qv2 = 0.f, qv3 = 0.f;
        #pragma unroll 8
        for (int k = 0; k < KNN; ++k) {
            int e = eL[p * KNN + k];
            float4 v = *(const float4*)&cfeat[((size_t)(bbase + e) << 7) + m * 4];
            mx0 = fmaxf(mx0, v.x); sv0 += v.x; qv0 = fmaf(v.x, v.x, qv0);
            mx1 = fmaxf(mx1, v.y); sv1 += v.y; qv1 = fmaf(v.y, v.y, qv1);
            mx2 = fmaxf(mx2, v.z); sv2 += v.z; qv2 = fmaf(v.z, v.z, qv2);
            mx3 = fmaxf(mx3, v.w); sv3 += v.w; qv3 = fmaf(v.w, v.w, qv3);
        }
        float4 a = *(const float4*)&afeat[((size_t)q << 7) + m * 4];
        float4 mo = make_float4(a.x + mx0, a.y + mx1, a.z + mx2, a.w + mx3);
        *(float4*)&M[((size_t)q << 7) + m * 4] = mo;
        s1[0] += fmaf(24.f, a.x, sv0); s2[0] += 24.f * a.x * a.x + 2.f * a.x * sv0 + qv0;
        s1[1] += fmaf(24.f, a.y, sv1); s2[1] += 24.f * a.y * a.y + 2.f * a.y * sv1 + qv1;
        s1[2] += fmaf(24.f, a.z, sv2); s2[2] += 24.f * a.z * a.z + 2.f * a.z * sv2 + qv2;
        s1[3] += fmaf(24.f, a.w, sv3); s2[3] += 24.f * a.w * a.w + 2.f * a.w * sv3 + qv3;
    }
    #pragma unroll
    for (int j = 0; j < 4; ++j) red[g][m * 4 + j] = s1[j];
    __syncthreads();
    if (threadIdx.x < 128) {
        float t = 0.f;
        #pragma unroll
        for (int gg = 0; gg < 8; ++gg) t += red[gg][threadIdx.x];
        atomicAdd(&st[threadIdx.x], t);
    }
    __syncthreads();
    #pragma unroll
    for (int j = 0; j < 4; ++j) red[g][m * 4 + j] = s2[j];
    __syncthreads();
    if (threadIdx.x < 128) {
        float t = 0.f;
        #pragma unroll
        for (int gg = 0; gg < 8; ++gg) t += red[gg][threadIdx.x];
        atomicAdd(&st[128 + threadIdx.x], t);
    }
}

// ============================================================
// Generic layer: (optional BN+act on input) -> x·W^T (+bias) ->
// raw output + per-channel (sum, sumsq) stats.
// XCD-affinity swizzle on the 256 x-blocks.
// ============================================================
template<int I, int O, int OSPLIT, int MODE>
__global__ __launch_bounds__(256) void layer_kernel(
    const float* __restrict__ inraw, const float* __restrict__ inst, float rcnt,
    const float* __restrict__ ing, const float* __restrict__ inbe,
    const float* __restrict__ W, const float* __restrict__ bias,
    const float* __restrict__ xyz, const float* __restrict__ pts,
    float* __restrict__ outraw, float* __restrict__ outst)
{
    constexpr int OH = O / OSPLIT;            // outputs handled by this block
    constexpr int IP = (I & 1) ? I : I + 1;   // odd stride: conflict-friendly
    constexpr int OP = OH + 4;                // mult-of-4 stride: b128-aligned
    constexpr int OW = OH / 16;
    __shared__ float inl[64 * IP];
    __shared__ float wl[64 * OP];
    __shared__ float ns[I], nb[I];

    int b, chunk;
    xcd_map(blockIdx.x, b, chunk);            // chunk in [0,64)
    int q0 = b * 4096 + chunk * 64;
    int o0 = blockIdx.y * OH;

    if (MODE != 0) {
        if (threadIdx.x < I) {
            int c = threadIdx.x;
            float m = inst[c] * rcnt;
            float v = inst[I + c] * rcnt - m * m;
            float inv = 1.0f / sqrtf(v + 1e-5f);
            float sc = inv * ing[c];
            ns[c] = sc;
            nb[c] = inbe[c] - m * sc;
        }
        __syncthreads();
        const float* src = inraw + (size_t)q0 * I;
        for (int idx = threadIdx.x; idx < 64 * I; idx += 256) {
            int p = idx / I, c = idx - p * I;
            float v = fmaf(src[idx], ns[c], nb[c]);
            if (MODE == 1) v = fmaxf(v, 0.0f);
            else           v = (v > 0.0f) ? v : 0.2f * v;
            inl[p * IP + c] = v;
        }
    } else {
        int n0 = q0 & 4095;
        for (int idx = threadIdx.x; idx < 64 * I; idx += 256) {
            int c = idx >> 6, p = idx & 63;
            float v;
            if (c < 3) v = xyz[((size_t)(b * 3 + c) << 12) + n0 + p];
            else       v = pts[((size_t)(b * 64 + (c - 3)) << 12) + n0 + p];
            inl[p * IP + c] = v;
        }
    }

    int ng = threadIdx.x & 15, og = threadIdx.x >> 4;
    float acc[4][OW];
    #pragma unroll
    for (int r = 0; r < 4; ++r)
        #pragma unroll
        for (int i = 0; i < OW; ++i) acc[r][i] = 0.f;

    for (int ct = 0; ct < I; ct += 64) {
        int CT = (I - ct < 64) ? (I - ct) : 64;
        __syncthreads();  // inl ready (iter 0) / previous wl consumed
        for (int idx = threadIdx.x; idx < CT * OH; idx += 256) {
            int o = idx / CT, cc = idx - o * CT;
            wl[cc * OP + o] = W[(size_t)(o0 + o) * I + ct + cc];
        }
        __syncthreads();
        for (int cc = 0; cc < CT; ++cc) {
            int c = ct + cc;
            float pv[4];
            #pragma unroll
            for (int r = 0; r < 4; ++r) pv[r] = inl[(ng * 4 + r) * IP + c];
            const float* wr = &wl[cc * OP + og * OW];
            if constexpr ((OW & 3) == 0) {
                #pragma unroll
                for (int i4 = 0; i4 < OW / 4; ++i4) {
                    float4 wv = *(const float4*)&wr[i4 * 4];
                    #pragma unroll
                    for (int r = 0; r < 4; ++r) {
                        acc[r][i4 * 4 + 0] = fmaf(pv[r], wv.x, acc[r][i4 * 4 + 0]);
                        acc[r][i4 * 4 + 1] = fmaf(pv[r], wv.y, acc[r][i4 * 4 + 1]);
                        acc[r][i4 * 4 + 2] = fmaf(pv[r], wv.z, acc[r][i4 * 4 + 2]);
                        acc[r][i4 * 4 + 3] = fmaf(pv[r], wv.w, acc[r][i4 * 4 + 3]);
                    }
                }
            } else {  // OW == 2
                float2 wv = *(const float2*)&wr[0];
                #pragma unroll
                for (int r = 0; r < 4; ++r) {
                    acc[r][0] = fmaf(pv[r], wv.x, acc[r][0]);
                    acc[r][1] = fmaf(pv[r], wv.y, acc[r][1]);
                }
            }
        }
    }

    if (bias != nullptr) {
        #pragma unroll
        for (int i = 0; i < OW; ++i) {
            float bv = bias[o0 + og * OW + i];
            #pragma unroll
            for (int r = 0; r < 4; ++r) acc[r][i] += bv;
        }
    }
    __syncthreads();
    // stage outputs (reuse wl) for coalesced store + stats
    #pragma unroll
    for (int r = 0; r < 4; ++r)
        #pragma unroll
        for (int i = 0; i < OW; ++i)
            wl[(ng * 4 + r) * OP + og * OW + i] = acc[r][i];
    __syncthreads();

    for (int idx = threadIdx.x; idx < 64 * OH; idx += 256) {
        int p = idx / OH, o = idx - p * OH;
        outraw[(size_t)(q0 + p) * O + o0 + o] = wl[p * OP + o];
    }
    if (threadIdx.x < OH) {
        int o = threadIdx.x;
        float s1 = 0.f, s2 = 0.f;
        #pragma unroll 8
        for (int p = 0; p < 64; ++p) {
            float v = wl[p * OP + o];
            s1 += v;
            s2 = fmaf(v, v, s2);
        }
        atomicAdd(&outst[o0 + o], s1);
        atomicAdd(&outst[O + o0 + o], s2);
    }
}

// ============================================================
// Fused finalize: BN + act + max over points for BOTH branches.
// grid (32, 8): y<4 -> graph branch (O=128, leaky) -> gg
//               y>=4 -> point branch (O=256, relu) -> pf
// ============================================================
__global__ __launch_bounds__(256) void fin2_kernel(const float* __restrict__ gm_raw,
                                                   const float* __restrict__ stGM,
                                                   const float* __restrict__ gm_g,
                                                   const float* __restrict__ gm_b,
                                                   const float* __restrict__ l2_raw,
                                                   const float* __restrict__ stL2,
                                                   const float* __restrict__ g2,
                                                   const float* __restrict__ be2,
                                                   unsigned* __restrict__ gg,
                                                   unsigned* __restrict__ pf) {
    const float rcnt = 1.0f / 16384.0f;
    int b = blockIdx.y & 3;
    int p0 = blockIdx.x * 128;
    if (blockIdx.y < 4) {
        int o = threadIdx.x & 127, rep = threadIdx.x >> 7;
        float m = stGM[o] * rcnt;
        float v = stGM[128 + o] * rcnt - m * m;
        float sc = gm_g[o] / sqrtf(v + 1e-5f);
        float sh = gm_b[o] - m * sc;
        float mx = -__builtin_inff();
        for (int p = rep; p < 128; p += 2) {
            float x = fmaf(gm_raw[(size_t)(b * 4096 + p0 + p) * 128 + o], sc, sh);
            x = (x > 0.0f) ? x : 0.2f * x;
            mx = fmaxf(mx, x);
        }
        atomicMax(&gg[b * 128 + o], fmap(mx));
    } else {
        int o = threadIdx.x;
        float m = stL2[o] * rcnt;
        float v = stL2[256 + o] * rcnt - m * m;
        float sc = g2[o] / sqrtf(v + 1e-5f);
        float sh = be2[o] - m * sc;
        float mx = -__builtin_inff();
        for (int p = 0; p < 128; ++p) {
            float x = fmaf(l2_raw[(size_t)(b * 4096 + p0 + p) * 256 + o], sc, sh);
            x = fmaxf(x, 0.0f);
            mx = fmaxf(mx, x);
        }
        atomicMax(&pf[b * 256 + o], fmap(mx));
    }
}

// ============================================================
// Final head: fused(384)·fu_w^T -> BN over B=4 -> leaky -> out
// ============================================================
__global__ __launch_bounds__(256) void final_kernel(const unsigned* __restrict__ pf,
                                                    const unsigned* __restrict__ gg,
                                                    const float* __restrict__ fu_w,
                                                    const float* __restrict__ fu_g,
                                                    const float* __restrict__ fu_b,
                                                    float* __restrict__ out) {
    __shared__ float fl[4 * 384];
    for (int idx = threadIdx.x; idx < 4 * 384; idx += 256) {
        int b = idx / 384, c = idx - b * 384;
        unsigned u = (c < 256) ? pf[b * 256 + c] : gg[b * 128 + (c - 256)];
        fl[idx] = funmap(u);
    }
    __syncthreads();
    int o = threadIdx.x;
    float f[4];
    #pragma unroll
    for (int b = 0; b < 4; ++b) {
        float acc = 0.f;
        for (int c = 0; c < 384; ++c) acc = fmaf(fl[b * 384 + c], fu_w[(size_t)o * 384 + c], acc);
        f[b] = acc;
    }
    float m = 0.25f * (f[0] + f[1] + f[2] + f[3]);
    float var = 0.f;
    #pragma unroll
    for (int b = 0; b < 4; ++b) { float t = f[b] - m; var = fmaf(t, t, var); }
    var *= 0.25f;
    float inv = 1.0f / sqrtf(var + 1e-5f);
    float gv = fu_g[o], bv = fu_b[o];
    #pragma unroll
    for (int b = 0; b < 4; ++b) {
        float x = (f[b] - m) * inv * gv + bv;
        x = (x > 0.0f) ? x : 0.2f * x;
        out[b * 256 + o] = x;
    }
}

extern "C" void kernel_launch(void* const* d_in, const int* in_sizes, int n_in,
                              void* d_out, int out_size, void* d_ws, size_t ws_size,
                              hipStream_t stream) {
    const float* xyz   = (const float*)d_in[0];
    const float* pts   = (const float*)d_in[1];
    const float* ec_w  = (const float*)d_in[2];
    const float* ec_g  = (const float*)d_in[3];
    const float* ec_b  = (const float*)d_in[4];
    const float* gm_w  = (const float*)d_in[5];
    const float* gm_g  = (const float*)d_in[6];
    const float* gm_b  = (const float*)d_in[7];
    const float* w0    = (const float*)d_in[8];
    const float* bias0 = (const float*)d_in[9];
    const float* g0    = (const float*)d_in[10];
    const float* be0   = (const float*)d_in[11];
    const float* w1    = (const float*)d_in[12];
    const float* bias1 = (const float*)d_in[13];
    const float* g1    = (const float*)d_in[14];
    const float* be1   = (const float*)d_in[15];
    const float* w2    = (const float*)d_in[16];
    const float* bias2 = (const float*)d_in[17];
    const float* g2    = (const float*)d_in[18];
    const float* be2   = (const float*)d_in[19];
    const float* fu_w  = (const float*)d_in[20];
    const float* fu_g  = (const float*)d_in[21];
    const float* fu_b  = (const float*)d_in[22];

    float* ws = (float*)d_ws;
    float* out = (float*)d_out;

    // zero stats + atomic-max buffers
    hipMemsetAsync(ws + ST_BASE, 0, ST_COUNT * sizeof(float), stream);

    // KNN (wave-cooperative, ballot-compaction)
    knn_kernel<<<dim3(NPTS / 4, 4), 256, 0, stream>>>(xyz, (int*)(ws + OFF_EDGES));

    // edge-conv decomposition (XCD-affine)
    feat_kernel<<<256, 256, 0, stream>>>(pts, ec_w, ws + OFF_A, ws + OFF_C);
    gather_stats_kernel<<<QN / 16, 256, 0, stream>>>(ws + OFF_A, ws + OFF_C, (int*)(ws + OFF_EDGES),
                                                     ws + OFF_M, ws + ST_BN1);

    // graph MLP: leaky(bn1(M)) @ gm_w^T -> gmraw + stats
    layer_kernel<128, 128, 2, 2><<<dim3(256, 2), 256, 0, stream>>>(
        ws + OFF_M, ws + ST_BN1, 1.0f / 393216.0f, ec_g, ec_b,
        gm_w, nullptr, nullptr, nullptr, ws + OFF_GM, ws + ST_GM);

    // point MLP
    layer_kernel<67, 64, 2, 0><<<dim3(256, 2), 256, 0, stream>>>(
        nullptr, nullptr, 0.f, nullptr, nullptr,
        w0, bias0, xyz, pts, ws + OFF_L0, ws + ST_L0);
    layer_kernel<64, 128, 2, 1><<<dim3(256, 2), 256, 0, stream>>>(
        ws + OFF_L0, ws + ST_L0, 1.0f / 16384.0f, g0, be0,
        w1, bias1, nullptr, nullptr, ws + OFF_L1, ws + ST_L1);
    layer_kernel<128, 256, 4, 1><<<dim3(256, 4), 256, 0, stream>>>(
        ws + OFF_L1, ws + ST_L1, 1.0f / 16384.0f, g1, be1,
        w2, bias2, nullptr, nullptr, ws + OFF_L2, ws + ST_L2);

    // fused reductions to per-batch features
    fin2_kernel<<<dim3(32, 8), 256, 0, stream>>>(
        ws + OFF_GM, ws + ST_GM, gm_g, gm_b,
        ws + OFF_L2, ws + ST_L2, g2, be2,
        (unsigned*)(ws + OFF_GG), (unsigned*)(ws + OFF_PF));

    // fused head
    final_kernel<<<1, 256, 0, stream>>>((unsigned*)(ws + OFF_PF), (unsigned*)(ws + OFF_GG),
                                        fu_w, fu_g, fu_b, out);
}

// Round 5
// 360.440 us; speedup vs baseline: 3.6105x; 1.0996x over previous
//
#include <hip/hip_runtime.h>

#define NPTS 4096
#define QN   16384
#define KNN  24

// ---- workspace offsets (float units) ----
static constexpr size_t OFF_EDGES = 0;                         // int[QN*24]
static constexpr size_t OFF_BIG   = 393216;
static constexpr size_t OFF_A     = OFF_BIG;                   // float[QN*128]
static constexpr size_t OFF_C     = OFF_BIG + 2097152;         // float[QN*128]
static constexpr size_t OFF_M     = OFF_BIG + 4194304;         // float[QN*128]
static constexpr size_t OFF_GM    = OFF_BIG + 6553600;         // float[QN*128]
static constexpr size_t OFF_L0    = OFF_GM + 2097152;          // float[QN*64]
static constexpr size_t OFF_L1    = OFF_L0 + 1048576;          // float[QN*128]
static constexpr size_t OFF_L2    = OFF_L1 + 2097152;          // float[QN*256]
static constexpr size_t ST_BASE   = OFF_L2 + 4194304;
static constexpr size_t ST_BN1    = ST_BASE;                   // 256
static constexpr size_t ST_GM     = ST_BASE + 256;             // 256
static constexpr size_t ST_L0     = ST_BASE + 512;             // 128
static constexpr size_t ST_L1     = ST_BASE + 640;             // 256
static constexpr size_t ST_L2     = ST_BASE + 896;             // 512
static constexpr size_t OFF_PF    = ST_BASE + 1408;            // 1024 uint
static constexpr size_t OFF_GG    = ST_BASE + 2432;            // 512 uint
static constexpr size_t ST_TICKET = ST_BASE + 2944;            // 1 uint
static constexpr int    ST_COUNT  = 2945;

__device__ inline unsigned fmap(float f) {
    unsigned u = __float_as_uint(f);
    return (u & 0x80000000u) ? ~u : (u | 0x80000000u);
}
__device__ inline float funmap(unsigned u) {
    unsigned v = (u & 0x80000000u) ? (u & 0x7fffffffu) : ~u;
    return __uint_as_float(v);
}

// XCD-affinity decode (XCD = flat bid % 8 heuristic): batch b owns XCD pair
// {2b,2b+1}. v in [0, 8*H) -> b = (v&7)>>1, t = 2*(v>>3)+(v&1) in [0, 2*H/... )
__device__ inline void xcd_decode(int v, int& b, int& t) {
    b = (v & 7) >> 1;
    t = ((v >> 3) << 1) | (v & 1);
}

// ============================================================
// Generic dense layer part (64 points x OH outputs per block),
// k-tiled (64-wide) input+weight staging, exact same FLOP order
// as previous rounds. MODE: 0 = concat(xyz,pts), 1 = relu(bn),
// 2 = leaky(bn).
// ============================================================
template<int I, int O, int OH, int MODE, bool HASBIAS>
__device__ void layer_part(unsigned char* smem, int b, int chunk, int o0,
    const float* __restrict__ inraw, const float* __restrict__ inst, float rcnt,
    const float* __restrict__ ing, const float* __restrict__ inbe,
    const float* __restrict__ W, const float* __restrict__ bias,
    const float* __restrict__ xyz, const float* __restrict__ pts,
    float* __restrict__ outraw, float* __restrict__ outst)
{
    constexpr int OW = OH / 16;
    constexpr int OP = OH + 4;
    float* ns  = (float*)smem;            // I
    float* nb  = ns + I;                  // I
    float* inl = nb + I;                  // 64*65
    float* wl  = inl + 64 * 65;           // 64*OP
    int q0 = b * 4096 + chunk * 64;

    if (MODE != 0) {
        if (threadIdx.x < I) {
            int c = threadIdx.x;
            float m = inst[c] * rcnt;
            float v = inst[I + c] * rcnt - m * m;
            float inv = 1.0f / sqrtf(v + 1e-5f);
            float sc = inv * ing[c];
            ns[c] = sc;
            nb[c] = inbe[c] - m * sc;
        }
    }

    int ng = threadIdx.x & 15, og = threadIdx.x >> 4;
    float acc[4][OW];
    #pragma unroll
    for (int r = 0; r < 4; ++r)
        #pragma unroll
        for (int i = 0; i < OW; ++i) acc[r][i] = 0.f;

    for (int ct = 0; ct < I; ct += 64) {
        int CT = (I - ct < 64) ? (I - ct) : 64;
        __syncthreads();  // ns/nb ready (iter 0) / prev tile consumed
        if (MODE == 0) {
            for (int idx = threadIdx.x; idx < CT * 64; idx += 256) {
                int c = idx >> 6, p = idx & 63;
                int ch = ct + c;
                float v = (ch < 3) ? xyz[((size_t)(b * 3 + ch) << 12) + chunk * 64 + p]
                                   : pts[((size_t)(b * 64 + ch - 3) << 12) + chunk * 64 + p];
                inl[p * 65 + c] = v;
            }
        } else {
            const float* src = inraw + (size_t)q0 * I + ct;
            for (int idx = threadIdx.x; idx < 64 * 64; idx += 256) {
                int p = idx >> 6, c = idx & 63;
                if (c < CT) {
                    float v = fmaf(src[(size_t)p * I + c], ns[ct + c], nb[ct + c]);
                    v = (MODE == 1) ? fmaxf(v, 0.0f) : ((v > 0.0f) ? v : 0.2f * v);
                    inl[p * 65 + c] = v;
                }
            }
        }
        if (CT == 64) {
            for (int idx = threadIdx.x; idx < 64 * OH; idx += 256) {
                int o = idx >> 6, cc = idx & 63;
                wl[cc * OP + o] = W[(size_t)(o0 + o) * I + ct + cc];
            }
        } else {
            for (int idx = threadIdx.x; idx < CT * OH; idx += 256) {
                int o = idx / CT, cc = idx - o * CT;
                wl[cc * OP + o] = W[(size_t)(o0 + o) * I + ct + cc];
            }
        }
        __syncthreads();
        for (int cc = 0; cc < CT; ++cc) {
            float pv[4];
            #pragma unroll
            for (int r = 0; r < 4; ++r) pv[r] = inl[(ng * 4 + r) * 65 + cc];
            const float* wr = &wl[cc * OP + og * OW];
            if constexpr (OW == 4) {
                float4 wv = *(const float4*)wr;
                #pragma unroll
                for (int r = 0; r < 4; ++r) {
                    acc[r][0] = fmaf(pv[r], wv.x, acc[r][0]);
                    acc[r][1] = fmaf(pv[r], wv.y, acc[r][1]);
                    acc[r][2] = fmaf(pv[r], wv.z, acc[r][2]);
                    acc[r][3] = fmaf(pv[r], wv.w, acc[r][3]);
                }
            } else {
                float2 wv = *(const float2*)wr;
                #pragma unroll
                for (int r = 0; r < 4; ++r) {
                    acc[r][0] = fmaf(pv[r], wv.x, acc[r][0]);
                    acc[r][1] = fmaf(pv[r], wv.y, acc[r][1]);
                }
            }
        }
    }

    if (HASBIAS) {
        #pragma unroll
        for (int i = 0; i < OW; ++i) {
            float bv = bias[o0 + og * OW + i];
            #pragma unroll
            for (int r = 0; r < 4; ++r) acc[r][i] += bv;
        }
    }
    __syncthreads();
    #pragma unroll
    for (int r = 0; r < 4; ++r)
        #pragma unroll
        for (int i = 0; i < OW; ++i)
            wl[(ng * 4 + r) * OP + og * OW + i] = acc[r][i];
    __syncthreads();

    for (int idx = threadIdx.x; idx < 64 * OH; idx += 256) {
        int p = idx / OH, o = idx - p * OH;
        outraw[(size_t)(q0 + p) * O + o0 + o] = wl[p * OP + o];
    }
    if (threadIdx.x < OH) {
        int o = threadIdx.x;
        float s1 = 0.f, s2 = 0.f;
        #pragma unroll 8
        for (int p = 0; p < 64; ++p) {
            float v = wl[p * OP + o];
            s1 += v;
            s2 = fmaf(v, v, s2);
        }
        atomicAdd(&outst[o0 + o], s1);
        atomicAdd(&outst[O + o0 + o], s2);
    }
}

// ============================================================
// Kernel A: knn (4096 units) | feat (2048 units) | zero (1 unit)
// ============================================================
__global__ __launch_bounds__(256) void kA(const float* __restrict__ xyz,
                                          const float* __restrict__ pts,
                                          const float* __restrict__ ec_w,
                                          int* __restrict__ edges,
                                          float* __restrict__ afeat,
                                          float* __restrict__ cfeat,
                                          float* __restrict__ stz) {
    __shared__ __align__(16) unsigned char smem[25856];
    int u = blockIdx.x;
    if (u < 4096) {
        // ---- wave-cooperative exact KNN (unchanged logic) ----
        float4* cand = (float4*)smem;                                 // 1024
        unsigned long long* bufall = (unsigned long long*)(smem + 16384);
        int b = u >> 10;
        int wave = threadIdx.x >> 6, lane = threadIdx.x & 63;
        int n = ((u & 1023) << 2) + wave;
        const float* xb = xyz + (size_t)b * 3 * 4096;
        unsigned long long* wbuf = bufall + wave * 128;

        float xq = xb[n], yq = xb[4096 + n], zq = xb[8192 + n];
        float sqq = __fadd_rn(__fadd_rn(__fmul_rn(xq, xq), __fmul_rn(yq, yq)), __fmul_rn(zq, zq));

        unsigned T = 0xFFFFFFFFu;
        int count = 0;

        auto reduce = [&]() {
            unsigned long long ka = (lane < count) ? wbuf[lane] : ~0ull;
            int ra = 0;
            if (count > 64) {
                unsigned long long kb = (lane + 64 < count) ? wbuf[lane + 64] : ~0ull;
                int rb = 0;
                for (int j = 0; j < count; ++j) {
                    unsigned long long kj = wbuf[j];
                    ra += (kj < ka);
                    rb += (kj < kb);
                }
                if (rb < 25) wbuf[rb] = kb;
            } else {
                for (int j = 0; j < count; ++j) {
                    unsigned long long kj = wbuf[j];
                    ra += (kj < ka);
                }
            }
            if (ra < 25) wbuf[ra] = ka;
            count = 25;
            T = (unsigned)(wbuf[24] >> 32);
        };

        for (int strip = 0; strip < 4; ++strip) {
            __syncthreads();
            for (int i = threadIdx.x; i < 1024; i += 256) {
                int j = strip * 1024 + i;
                float x = xb[j], y = xb[4096 + j], z = xb[8192 + j];
                float sq = __fadd_rn(__fadd_rn(__fmul_rn(x, x), __fmul_rn(y, y)), __fmul_rn(z, z));
                cand[i] = make_float4(x, y, z, sq);
            }
            __syncthreads();
            for (int t = 0; t < 16; ++t) {
                float4 cv = cand[t * 64 + lane];
                float dot = __fadd_rn(__fadd_rn(__fmul_rn(xq, cv.x), __fmul_rn(yq, cv.y)), __fmul_rn(zq, cv.z));
                float d = __fsub_rn(__fadd_rn(sqq, cv.w), __fmul_rn(2.0f, dot));
                unsigned du = fmap(d);
                bool surv = (du <= T);
                unsigned long long m = __ballot(surv);
                if (m) {
                    if (surv) {
                        int ofs = __popcll(m & ((1ull << lane) - 1ull));
                        unsigned idx = (unsigned)(strip * 1024 + t * 64 + lane);
                        wbuf[count + ofs] = ((unsigned long long)du << 32) | idx;
                    }
                    count += (int)__popcll(m);
                    if (count >= 64) reduce();
                }
            }
        }
        reduce();
        if (lane >= 1 && lane < 25)
            edges[((size_t)(b * 4096 + n)) * KNN + lane - 1] = (int)(unsigned)(wbuf[lane] & 0xFFFFFFFFull);
    } else if (u < 6144) {
        // ---- feat: one 64x32 GEMM slice (a or c) per block ----
        int v = u - 4096;
        int b, t;
        xcd_decode(v, b, t);                  // t in [0, 512)
        int nchunk = t & 63, sub = t >> 6;    // sub in [0,8)
        int which = sub >> 2;                 // 0 = a (w1-w2), 1 = c (w2)
        int o0 = (sub & 3) * 32;
        int n0 = nchunk * 64;

        float* inl = (float*)smem;            // 64*65
        float* wl  = (float*)(smem + 16640);  // 64*36
        const float* pb = pts + (size_t)b * 64 * 4096;

        for (int idx = threadIdx.x; idx < 64 * 64; idx += 256) {
            int c = idx >> 6, p = idx & 63;
            inl[p * 65 + c] = pb[(size_t)c * 4096 + n0 + p];
        }
        for (int idx = threadIdx.x; idx < 64 * 32; idx += 256) {
            int cc = idx & 63, o = idx >> 6;
            float w2v = ec_w[(o0 + o) * 128 + 64 + cc];
            wl[cc * 36 + o] = which ? w2v : (ec_w[(o0 + o) * 128 + cc] - w2v);
        }
        __syncthreads();

        int ng = threadIdx.x & 15, og = threadIdx.x >> 4;
        float acc[4][2] = {{0.f, 0.f}, {0.f, 0.f}, {0.f, 0.f}, {0.f, 0.f}};
        for (int cc = 0; cc < 64; ++cc) {
            float pv[4];
            #pragma unroll
            for (int r = 0; r < 4; ++r) pv[r] = inl[(ng * 4 + r) * 65 + cc];
            float2 wv = *(const float2*)&wl[cc * 36 + og * 2];
            #pragma unroll
            for (int r = 0; r < 4; ++r) {
                acc[r][0] = fmaf(pv[r], wv.x, acc[r][0]);
                acc[r][1] = fmaf(pv[r], wv.y, acc[r][1]);
            }
        }
        __syncthreads();
        #pragma unroll
        for (int r = 0; r < 4; ++r) {
            wl[(ng * 4 + r) * 36 + og * 2 + 0] = acc[r][0];
            wl[(ng * 4 + r) * 36 + og * 2 + 1] = acc[r][1];
        }
        __syncthreads();
        float* dst = (which ? cfeat : afeat) + ((size_t)(b * 4096 + n0)) * 128 + o0;
        for (int idx = threadIdx.x; idx < 64 * 32; idx += 256) {
            int p = idx >> 5, o = idx & 31;
            dst[(size_t)p * 128 + o] = wl[p * 36 + o];
        }
    } else {
        for (int i = threadIdx.x; i < ST_COUNT; i += 256) stz[i] = 0.f;
    }
}

// ============================================================
// Kernel B: gather (1024 units) | L0 layer (512 units)
// ============================================================
__global__ __launch_bounds__(256) void kB(const float* __restrict__ afeat,
                                          const float* __restrict__ cfeat,
                                          const int* __restrict__ edges,
                                          float* __restrict__ M,
                                          float* __restrict__ stBN1,
                                          const float* __restrict__ xyz,
                                          const float* __restrict__ pts,
                                          const float* __restrict__ w0,
                                          const float* __restrict__ bias0,
                                          float* __restrict__ l0raw,
                                          float* __restrict__ stL0) {
    __shared__ __align__(16) unsigned char smem[26368];
    int u = blockIdx.x;
    if (u < 1024) {
        // ---- neighbor gather + BN1 stats ----
        int* eL = (int*)smem;                       // 16*24
        float* red = (float*)(smem + 1536);         // 8*132
        int b, chunk;
        xcd_decode(u, b, chunk);                    // chunk in [0,256)
        int q0 = b * 4096 + chunk * 16;
        for (int idx = threadIdx.x; idx < 16 * KNN; idx += 256) eL[idx] = edges[(size_t)q0 * KNN + idx];
        __syncthreads();

        int m = threadIdx.x & 31;
        int g = threadIdx.x >> 5;
        int bbase = b << 12;
        float s1[4] = {0.f, 0.f, 0.f, 0.f}, s2[4] = {0.f, 0.f, 0.f, 0.f};

        #pragma unroll
        for (int half = 0; half < 2; ++half) {
            int p = g + half * 8;
            int q = q0 + p;
            float mx0 = -__builtin_inff(), mx1 = mx0, mx2 = mx0, mx3 = mx0;
            float sv0 = 0.f, sv1 = 0.f, sv2 = 0.f, sv3 = 0.f;
            float qv0 = 0.f, qv1 = 0.f, qv2 = 0.f, qv3 = 0.f;
            #pragma unroll 8
            for (int k = 0; k < KNN; ++k) {
                int e = eL[p * KNN + k];
                float4 v = *(const float4*)&cfeat[((size_t)(bbase + e) << 7) + m * 4];
                mx0 = fmaxf(mx0, v.x); sv0 += v.x; qv0 = fmaf(v.x, v.x, qv0);
                mx1 = fmaxf(mx1, v.y); sv1 += v.y; qv1 = fmaf(v.y, v.y, qv1);
                mx2 = fmaxf(mx2, v.z); sv2 += v.z; qv2 = fmaf(v.z, v.z, qv2);
                mx3 = fmaxf(mx3, v.w); sv3 += v.w; qv3 = fmaf(v.w, v.w, qv3);
            }
            float4 a = *(const float4*)&afeat[((size_t)q << 7) + m * 4];
            float4 mo = make_float4(a.x + mx0, a.y + mx1, a.z + mx2, a.w + mx3);
            *(float4*)&M[((size_t)q << 7) + m * 4] = mo;
            s1[0] += fmaf(24.f, a.x, sv0); s2[0] += 24.f * a.x * a.x + 2.f * a.x * sv0 + qv0;
            s1[1] += fmaf(24.f, a.y, sv1); s2[1] += 24.f * a.y * a.y + 2.f * a.y * sv1 + qv1;
            s1[2] += fmaf(24.f, a.z, sv2); s2[2] += 24.f * a.z * a.z + 2.f * a.z * sv2 + qv2;
            s1[3] += fmaf(24.f, a.w, sv3); s2[3] += 24.f * a.w * a.w + 2.f * a.w * sv3 + qv3;
        }
        #pragma unroll
        for (int j = 0; j < 4; ++j) red[g * 132 + m * 4 + j] = s1[j];
        __syncthreads();
        if (threadIdx.x < 128) {
            float t = 0.f;
            #pragma unroll
            for (int gg = 0; gg < 8; ++gg) t += red[gg * 132 + threadIdx.x];
            atomicAdd(&stBN1[threadIdx.x], t);
        }
        __syncthreads();
        #pragma unroll
        for (int j = 0; j < 4; ++j) red[g * 132 + m * 4 + j] = s2[j];
        __syncthreads();
        if (threadIdx.x < 128) {
            float t = 0.f;
            #pragma unroll
            for (int gg = 0; gg < 8; ++gg) t += red[gg * 132 + threadIdx.x];
            atomicAdd(&stBN1[128 + threadIdx.x], t);
        }
    } else {
        int v = u - 1024;
        int b, t;
        xcd_decode(v, b, t);                // t in [0,128)
        int chunk = t & 63, y = t >> 6;     // y in {0,1}
        layer_part<67, 64, 32, 0, true>(smem, b, chunk, y * 32,
            nullptr, nullptr, 0.f, nullptr, nullptr,
            w0, bias0, xyz, pts, l0raw, stL0);
    }
}

// ============================================================
// Kernel C: GM layer (512 units) | L1 layer (512 units)
// ============================================================
__global__ __launch_bounds__(256) void kC(const float* __restrict__ M,
                                          const float* __restrict__ stBN1,
                                          const float* __restrict__ ec_g,
                                          const float* __restrict__ ec_b,
                                          const float* __restrict__ gm_w,
                                          float* __restrict__ gmraw,
                                          float* __restrict__ stGM,
                                          const float* __restrict__ l0raw,
                                          const float* __restrict__ stL0,
                                          const float* __restrict__ g0,
                                          const float* __restrict__ be0,
                                          const float* __restrict__ w1,
                                          const float* __restrict__ bias1,
                                          float* __restrict__ l1raw,
                                          float* __restrict__ stL1) {
    __shared__ __align__(16) unsigned char smem[35072];
    int u = blockIdx.x;
    if (u < 512) {
        int b, t;
        xcd_decode(u, b, t);                // t in [0,128)
        int chunk = t & 63, y = t >> 6;
        layer_part<128, 128, 64, 2, false>(smem, b, chunk, y * 64,
            M, stBN1, 1.0f / 393216.0f, ec_g, ec_b,
            gm_w, nullptr, nullptr, nullptr, gmraw, stGM);
    } else {
        int v = u - 512;
        int b, t;
        xcd_decode(v, b, t);
        int chunk = t & 63, y = t >> 6;
        layer_part<64, 128, 64, 1, true>(smem, b, chunk, y * 64,
            l0raw, stL0, 1.0f / 16384.0f, g0, be0,
            w1, bias1, nullptr, nullptr, l1raw, stL1);
    }
}

// ============================================================
// Kernel D: L2 layer (1024 units)
// ============================================================
__global__ __launch_bounds__(256) void kD(const float* __restrict__ l1raw,
                                          const float* __restrict__ stL1,
                                          const float* __restrict__ g1,
                                          const float* __restrict__ be1,
                                          const float* __restrict__ w2,
                                          const float* __restrict__ bias2,
                                          float* __restrict__ l2raw,
                                          float* __restrict__ stL2) {
    __shared__ __align__(16) unsigned char smem[35072];
    int u = blockIdx.x;
    int b, t;
    xcd_decode(u, b, t);                    // t in [0,256)
    int chunk = t & 63, y = t >> 6;         // y in [0,4)
    layer_part<128, 256, 64, 1, true>(smem, b, chunk, y * 64,
        l1raw, stL1, 1.0f / 16384.0f, g1, be1,
        w2, bias2, nullptr, nullptr, l2raw, stL2);
}

// ============================================================
// Kernel E: fused finalize (256 units) + last-block final head
// ============================================================
__global__ __launch_bounds__(256) void kE(const float* __restrict__ gm_raw,
                                          const float* __restrict__ stGM,
                                          const float* __restrict__ gm_g,
                                          const float* __restrict__ gm_b,
                                          const float* __restrict__ l2_raw,
                                          const float* __restrict__ stL2,
                                          const float* __restrict__ g2,
                                          const float* __restrict__ be2,
                                          unsigned* __restrict__ gg,
                                          unsigned* __restrict__ pf,
                                          unsigned* __restrict__ ticket,
                                          const float* __restrict__ fu_w,
                                          const float* __restrict__ fu_g,
                                          const float* __restrict__ fu_b,
                                          float* __restrict__ out) {
    __shared__ __align__(16) unsigned char smem[6400];
    __shared__ int isLast;
    const float rcnt = 1.0f / 16384.0f;
    int u = blockIdx.x;
    int y = u >> 5, x = u & 31;
    int b = y & 3;
    int p0 = x * 128;
    if (y < 4) {
        int o = threadIdx.x & 127, rep = threadIdx.x >> 7;
        float m = stGM[o] * rcnt;
        float v = stGM[128 + o] * rcnt - m * m;
        float sc = gm_g[o] / sqrtf(v + 1e-5f);
        float sh = gm_b[o] - m * sc;
        float mx = -__builtin_inff();
        for (int p = rep; p < 128; p += 2) {
            float xx = fmaf(gm_raw[(size_t)(b * 4096 + p0 + p) * 128 + o], sc, sh);
            xx = (xx > 0.0f) ? xx : 0.2f * xx;
            mx = fmaxf(mx, xx);
        }
        atomicMax(&gg[b * 128 + o], fmap(mx));
    } else {
        int o = threadIdx.x;
        float m = stL2[o] * rcnt;
        float v = stL2[256 + o] * rcnt - m * m;
        float sc = g2[o] / sqrtf(v + 1e-5f);
        float sh = be2[o] - m * sc;
        float mx = -__builtin_inff();
        for (int p = 0; p < 128; ++p) {
            float xx = fmaf(l2_raw[(size_t)(b * 4096 + p0 + p) * 256 + o], sc, sh);
            xx = fmaxf(xx, 0.0f);
            mx = fmaxf(mx, xx);
        }
        atomicMax(&pf[b * 256 + o], fmap(mx));
    }
    __syncthreads();
    if (threadIdx.x == 0) {
        __threadfence();
        unsigned old = atomicAdd(ticket, 1u);
        isLast = (old == 255u);
    }
    __syncthreads();
    if (isLast) {
        float* fl = (float*)smem;   // 4*384
        for (int idx = threadIdx.x; idx < 4 * 384; idx += 256) {
            int bb = idx / 384, c = idx - bb * 384;
            unsigned uu = (c < 256) ? atomicMax(&pf[bb * 256 + c], 0u)
                                    : atomicMax(&gg[bb * 128 + (c - 256)], 0u);
            fl[idx] = funmap(uu);
        }
        __syncthreads();
        int o = threadIdx.x;
        float f[4];
        #pragma unroll
        for (int bb = 0; bb < 4; ++bb) {
            float acc = 0.f;
            for (int c = 0; c < 384; ++c) acc = fmaf(fl[bb * 384 + c], fu_w[(size_t)o * 384 + c], acc);
            f[bb] = acc;
        }
        float m = 0.25f * (f[0] + f[1] + f[2] + f[3]);
        float var = 0.f;
        #pragma unroll
        for (int bb = 0; bb < 4; ++bb) { float tt = f[bb] - m; var = fmaf(tt, tt, var); }
        var *= 0.25f;
        float inv = 1.0f / sqrtf(var + 1e-5f);
        float gv = fu_g[o], bv = fu_b[o];
        #pragma unroll
        for (int bb = 0; bb < 4; ++bb) {
            float xx = (f[bb] - m) * inv * gv + bv;
            xx = (xx > 0.0f) ? xx : 0.2f * xx;
            out[bb * 256 + o] = xx;
        }
    }
}

extern "C" void kernel_launch(void* const* d_in, const int* in_sizes, int n_in,
                              void* d_out, int out_size, void* d_ws, size_t ws_size,
                              hipStream_t stream) {
    const float* xyz   = (const float*)d_in[0];
    const float* pts   = (const float*)d_in[1];
    const float* ec_w  = (const float*)d_in[2];
    const float* ec_g  = (const float*)d_in[3];
    const float* ec_b  = (const float*)d_in[4];
    const float* gm_w  = (const float*)d_in[5];
    const float* gm_g  = (const float*)d_in[6];
    const float* gm_b  = (const float*)d_in[7];
    const float* w0    = (const float*)d_in[8];
    const float* bias0 = (const float*)d_in[9];
    const float* g0    = (const float*)d_in[10];
    const float* be0   = (const float*)d_in[11];
    const float* w1    = (const float*)d_in[12];
    const float* bias1 = (const float*)d_in[13];
    const float* g1    = (const float*)d_in[14];
    const float* be1   = (const float*)d_in[15];
    const float* w2    = (const float*)d_in[16];
    const float* bias2 = (const float*)d_in[17];
    const float* g2    = (const float*)d_in[18];
    const float* be2   = (const float*)d_in[19];
    const float* fu_w  = (const float*)d_in[20];
    const float* fu_g  = (const float*)d_in[21];
    const float* fu_b  = (const float*)d_in[22];

    float* ws = (float*)d_ws;
    float* out = (float*)d_out;

    // A: knn | feat | zero-stats           (4096 + 2048 + 1 blocks)
    kA<<<6145, 256, 0, stream>>>(xyz, pts, ec_w, (int*)(ws + OFF_EDGES),
                                 ws + OFF_A, ws + OFF_C, ws + ST_BASE);
    // B: gather | L0                       (1024 + 512)
    kB<<<1536, 256, 0, stream>>>(ws + OFF_A, ws + OFF_C, (int*)(ws + OFF_EDGES),
                                 ws + OFF_M, ws + ST_BN1,
                                 xyz, pts, w0, bias0, ws + OFF_L0, ws + ST_L0);
    // C: GM | L1                           (512 + 512)
    kC<<<1024, 256, 0, stream>>>(ws + OFF_M, ws + ST_BN1, ec_g, ec_b, gm_w,
                                 ws + OFF_GM, ws + ST_GM,
                                 ws + OFF_L0, ws + ST_L0, g0, be0, w1, bias1,
                                 ws + OFF_L1, ws + ST_L1);
    // D: L2                                (1024)
    kD<<<1024, 256, 0, stream>>>(ws + OFF_L1, ws + ST_L1, g1, be1, w2, bias2,
                                 ws + OFF_L2, ws + ST_L2);
    // E: fin2 + final (ticketed)           (256)
    kE<<<256, 256, 0, stream>>>(ws + OFF_GM, ws + ST_GM, gm_g, gm_b,
                                ws + OFF_L2, ws + ST_L2, g2, be2,
                                (unsigned*)(ws + OFF_GG), (unsigned*)(ws + OFF_PF),
                                (unsigned*)(ws + ST_TICKET),
                                fu_w, fu_g, fu_b, out);
}

// Round 6
// 320.362 us; speedup vs baseline: 4.0622x; 1.1251x over previous
//
#include <hip/hip_runtime.h>

#define NPTS 4096
#define QN   16384
#define KNN  24

// ---- workspace offsets (float units) ----
static constexpr size_t OFF_EDGES = 0;                         // int[QN*24]
static constexpr size_t OFF_BIG   = 393216;
static constexpr size_t OFF_A     = OFF_BIG;                   // float[QN*128]
static constexpr size_t OFF_C     = OFF_BIG + 2097152;         // float[QN*128]
static constexpr size_t OFF_M     = OFF_BIG + 4194304;         // float[QN*128]
static constexpr size_t OFF_L0    = OFF_BIG + 6553600;         // float[QN*64]
static constexpr size_t OFF_L1    = OFF_L0 + 1048576;          // float[QN*128]
static constexpr size_t ST_BASE   = OFF_L1 + 2097152;
static constexpr size_t ST_BN1    = ST_BASE;                   // 256
static constexpr size_t ST_GM     = ST_BASE + 256;             // 256
static constexpr size_t ST_L0     = ST_BASE + 512;             // 128
static constexpr size_t ST_L1     = ST_BASE + 640;             // 256
static constexpr size_t ST_L2     = ST_BASE + 896;             // 512
static constexpr size_t RMX_GM    = ST_BASE + 1408;            // 512 uint
static constexpr size_t RMN_GM    = ST_BASE + 1920;            // 512 uint
static constexpr size_t RMX_L2    = ST_BASE + 2432;            // 1024 uint
static constexpr size_t RMN_L2    = ST_BASE + 3456;            // 1024 uint
static constexpr int    ST_COUNT  = 4480;

__device__ inline unsigned fmap(float f) {
    unsigned u = __float_as_uint(f);
    return (u & 0x80000000u) ? ~u : (u | 0x80000000u);
}
__device__ inline float funmap(unsigned u) {
    unsigned v = (u & 0x80000000u) ? (u & 0x7fffffffu) : ~u;
    return __uint_as_float(v);
}

// XCD-affinity decode: batch b owns XCD pair {2b,2b+1} (XCD = bid%8 heuristic)
__device__ inline void xcd_decode(int v, int& b, int& t) {
    b = (v & 7) >> 1;
    t = ((v >> 3) << 1) | (v & 1);
}

// ============================================================
// Dense layer part v2: 64 points x OH outputs per block.
// inl transposed [cc][p] (stride 68) -> pv = 1 ds_read_b128;
// wl [cc][o] (stride OH+4) -> wv = broadcast b128 reads.
// MODE: 0 = concat(xyz,pts), 1 = relu(bn), 2 = leaky(bn).
// WRITE_RAW: store raw outputs. MINMAX: per-(b,ch) raw extremes
// via atomicMax/Min (monotone-pushthrough for later max-reduce).
// ============================================================
template<int I, int O, int OH, int MODE, bool HASBIAS, bool WRITE_RAW, bool MINMAX>
__device__ void layer_part(unsigned char* smem, int b, int chunk, int o0,
    const float* __restrict__ inraw, const float* __restrict__ inst, float rcnt,
    const float* __restrict__ ing, const float* __restrict__ inbe,
    const float* __restrict__ W, const float* __restrict__ bias,
    const float* __restrict__ xyz, const float* __restrict__ pts,
    float* __restrict__ outraw, float* __restrict__ outst,
    unsigned* __restrict__ rmax, unsigned* __restrict__ rmin)
{
    constexpr int OP = OH + 4;
    constexpr int OW = OH / 16;
    float* ns  = (float*)smem;                     // I
    float* nb  = ns + I;                           // I
    float* inl = (float*)(smem + 1024);            // [64 cc][68]
    float* wl  = (float*)(smem + 1024 + 17408);    // [64 cc][OP]
    int q0 = b * 4096 + chunk * 64;

    if (MODE != 0) {
        if (threadIdx.x < I) {
            int c = threadIdx.x;
            float m = inst[c] * rcnt;
            float v = inst[I + c] * rcnt - m * m;
            float inv = 1.0f / sqrtf(v + 1e-5f);
            float sc = inv * ing[c];
            ns[c] = sc;
            nb[c] = inbe[c] - m * sc;
        }
    }

    int ng = threadIdx.x & 15, og = threadIdx.x >> 4;
    float acc[4][OW];
    #pragma unroll
    for (int r = 0; r < 4; ++r)
        #pragma unroll
        for (int i = 0; i < OW; ++i) acc[r][i] = 0.f;

    for (int ct = 0; ct < I; ct += 64) {
        int CT = (I - ct < 64) ? (I - ct) : 64;
        __syncthreads();  // ns/nb ready (iter 0) / prev tile consumed
        if (MODE == 0) {
            for (int idx = threadIdx.x; idx < CT * 64; idx += 256) {
                int c = idx >> 6, p = idx & 63;
                int ch = ct + c;
                float v = (ch < 3) ? xyz[((size_t)(b * 3 + ch) << 12) + chunk * 64 + p]
                                   : pts[((size_t)(b * 64 + ch - 3) << 12) + chunk * 64 + p];
                inl[c * 68 + p] = v;
            }
        } else {
            const float* src = inraw + (size_t)q0 * I + ct;
            #pragma unroll
            for (int it = 0; it < 4; ++it) {
                int idx = threadIdx.x + it * 256;   // CT==64 here (I = 64 or 128)
                int c = idx & 63, pq = idx >> 6;
                float sc_ = ns[ct + c], sh_ = nb[ct + c];
                float4 v;
                v.x = fmaf(src[(size_t)(pq * 4 + 0) * I + c], sc_, sh_);
                v.y = fmaf(src[(size_t)(pq * 4 + 1) * I + c], sc_, sh_);
                v.z = fmaf(src[(size_t)(pq * 4 + 2) * I + c], sc_, sh_);
                v.w = fmaf(src[(size_t)(pq * 4 + 3) * I + c], sc_, sh_);
                if (MODE == 1) {
                    v.x = fmaxf(v.x, 0.f); v.y = fmaxf(v.y, 0.f);
                    v.z = fmaxf(v.z, 0.f); v.w = fmaxf(v.w, 0.f);
                } else {
                    v.x = (v.x > 0.f) ? v.x : 0.2f * v.x;
                    v.y = (v.y > 0.f) ? v.y : 0.2f * v.y;
                    v.z = (v.z > 0.f) ? v.z : 0.2f * v.z;
                    v.w = (v.w > 0.f) ? v.w : 0.2f * v.w;
                }
                *(float4*)&inl[c * 68 + pq * 4] = v;
            }
        }
        if ((I & 3) == 0) {
            for (int idx = threadIdx.x; idx < (CT / 4) * OH; idx += 256) {
                int cq = idx & 15, o = idx >> 4;
                float4 wv4 = *(const float4*)&W[(size_t)(o0 + o) * I + ct + cq * 4];
                wl[(cq * 4 + 0) * OP + o] = wv4.x;
                wl[(cq * 4 + 1) * OP + o] = wv4.y;
                wl[(cq * 4 + 2) * OP + o] = wv4.z;
                wl[(cq * 4 + 3) * OP + o] = wv4.w;
            }
        } else {
            for (int idx = threadIdx.x; idx < CT * OH; idx += 256) {
                int o = idx / CT, cc = idx - o * CT;
                wl[cc * OP + o] = W[(size_t)(o0 + o) * I + ct + cc];
            }
        }
        __syncthreads();
        for (int cc = 0; cc < CT; ++cc) {
            float4 pv = *(const float4*)&inl[cc * 68 + ng * 4];
            float pvv[4] = {pv.x, pv.y, pv.z, pv.w};
            #pragma unroll
            for (int i4 = 0; i4 < OW / 4; ++i4) {
                float4 wv = *(const float4*)&wl[cc * OP + og * OW + i4 * 4];
                #pragma unroll
                for (int r = 0; r < 4; ++r) {
                    acc[r][i4 * 4 + 0] = fmaf(pvv[r], wv.x, acc[r][i4 * 4 + 0]);
                    acc[r][i4 * 4 + 1] = fmaf(pvv[r], wv.y, acc[r][i4 * 4 + 1]);
                    acc[r][i4 * 4 + 2] = fmaf(pvv[r], wv.z, acc[r][i4 * 4 + 2]);
                    acc[r][i4 * 4 + 3] = fmaf(pvv[r], wv.w, acc[r][i4 * 4 + 3]);
                }
            }
        }
    }

    if (HASBIAS) {
        #pragma unroll
        for (int i = 0; i < OW; ++i) {
            float bv = bias[o0 + og * OW + i];
            #pragma unroll
            for (int r = 0; r < 4; ++r) acc[r][i] += bv;
        }
    }
    __syncthreads();
    #pragma unroll
    for (int r = 0; r < 4; ++r)
        #pragma unroll
        for (int i = 0; i < OW; ++i)
            wl[(ng * 4 + r) * OP + og * OW + i] = acc[r][i];
    __syncthreads();

    if (WRITE_RAW) {
        for (int idx = threadIdx.x; idx < 64 * OH; idx += 256) {
            int p = idx / OH, o = idx - p * OH;
            outraw[(size_t)(q0 + p) * O + o0 + o] = wl[p * OP + o];
        }
    }
    if (threadIdx.x < OH) {
        int o = threadIdx.x;
        float s1 = 0.f, s2 = 0.f;
        float mx = -__builtin_inff(), mn = __builtin_inff();
        #pragma unroll 8
        for (int p = 0; p < 64; ++p) {
            float v = wl[p * OP + o];
            s1 += v;
            s2 = fmaf(v, v, s2);
            if (MINMAX) { mx = fmaxf(mx, v); mn = fminf(mn, v); }
        }
        atomicAdd(&outst[o0 + o], s1);
        atomicAdd(&outst[O + o0 + o], s2);
        if (MINMAX) {
            atomicMax(&rmax[b * O + o0 + o], fmap(mx));
            atomicMin(&rmin[b * O + o0 + o], fmap(mn));
        }
    }
}

// ============================================================
// Kernel A: knn (4096) | feat (2048) | init stats/extremes (1)
// ============================================================
__global__ __launch_bounds__(256) void kA(const float* __restrict__ xyz,
                                          const float* __restrict__ pts,
                                          const float* __restrict__ ec_w,
                                          int* __restrict__ edges,
                                          float* __restrict__ afeat,
                                          float* __restrict__ cfeat,
                                          unsigned* __restrict__ stz) {
    __shared__ __align__(16) unsigned char smem[25856];
    int u = blockIdx.x;
    if (u < 4096) {
        // ---- wave-cooperative exact KNN (ballot-compaction, unchanged) ----
        float4* cand = (float4*)smem;
        unsigned long long* bufall = (unsigned long long*)(smem + 16384);
        int b = u >> 10;
        int wave = threadIdx.x >> 6, lane = threadIdx.x & 63;
        int n = ((u & 1023) << 2) + wave;
        const float* xb = xyz + (size_t)b * 3 * 4096;
        unsigned long long* wbuf = bufall + wave * 128;

        float xq = xb[n], yq = xb[4096 + n], zq = xb[8192 + n];
        float sqq = __fadd_rn(__fadd_rn(__fmul_rn(xq, xq), __fmul_rn(yq, yq)), __fmul_rn(zq, zq));

        unsigned T = 0xFFFFFFFFu;
        int count = 0;

        auto reduce = [&]() {
            unsigned long long ka = (lane < count) ? wbuf[lane] : ~0ull;
            int ra = 0;
            if (count > 64) {
                unsigned long long kb = (lane + 64 < count) ? wbuf[lane + 64] : ~0ull;
                int rb = 0;
                for (int j = 0; j < count; ++j) {
                    unsigned long long kj = wbuf[j];
                    ra += (kj < ka);
                    rb += (kj < kb);
                }
                if (rb < 25) wbuf[rb] = kb;
            } else {
                for (int j = 0; j < count; ++j) {
                    unsigned long long kj = wbuf[j];
                    ra += (kj < ka);
                }
            }
            if (ra < 25) wbuf[ra] = ka;
            count = 25;
            T = (unsigned)(wbuf[24] >> 32);
        };

        for (int strip = 0; strip < 4; ++strip) {
            __syncthreads();
            for (int i = threadIdx.x; i < 1024; i += 256) {
                int j = strip * 1024 + i;
                float x = xb[j], y = xb[4096 + j], z = xb[8192 + j];
                float sq = __fadd_rn(__fadd_rn(__fmul_rn(x, x), __fmul_rn(y, y)), __fmul_rn(z, z));
                cand[i] = make_float4(x, y, z, sq);
            }
            __syncthreads();
            for (int t = 0; t < 16; ++t) {
                float4 cv = cand[t * 64 + lane];
                float dot = __fadd_rn(__fadd_rn(__fmul_rn(xq, cv.x), __fmul_rn(yq, cv.y)), __fmul_rn(zq, cv.z));
                float d = __fsub_rn(__fadd_rn(sqq, cv.w), __fmul_rn(2.0f, dot));
                unsigned du = fmap(d);
                bool surv = (du <= T);
                unsigned long long m = __ballot(surv);
                if (m) {
                    if (surv) {
                        int ofs = __popcll(m & ((1ull << lane) - 1ull));
                        unsigned idx = (unsigned)(strip * 1024 + t * 64 + lane);
                        wbuf[count + ofs] = ((unsigned long long)du << 32) | idx;
                    }
                    count += (int)__popcll(m);
                    if (count >= 64) reduce();
                }
            }
        }
        reduce();
        if (lane >= 1 && lane < 25)
            edges[((size_t)(b * 4096 + n)) * KNN + lane - 1] = (int)(unsigned)(wbuf[lane] & 0xFFFFFFFFull);
    } else if (u < 6144) {
        // ---- feat: one 64x32 GEMM slice (a or c) per block ----
        int v = u - 4096;
        int b, t;
        xcd_decode(v, b, t);                  // t in [0, 512)
        int nchunk = t & 63, sub = t >> 6;
        int which = sub >> 2;
        int o0 = (sub & 3) * 32;
        int n0 = nchunk * 64;

        float* inl = (float*)smem;            // 64*65
        float* wl  = (float*)(smem + 16640);  // 64*36
        const float* pb = pts + (size_t)b * 64 * 4096;

        for (int idx = threadIdx.x; idx < 64 * 64; idx += 256) {
            int c = idx >> 6, p = idx & 63;
            inl[p * 65 + c] = pb[(size_t)c * 4096 + n0 + p];
        }
        for (int idx = threadIdx.x; idx < 64 * 32; idx += 256) {
            int cc = idx & 63, o = idx >> 6;
            float w2v = ec_w[(o0 + o) * 128 + 64 + cc];
            wl[cc * 36 + o] = which ? w2v : (ec_w[(o0 + o) * 128 + cc] - w2v);
        }
        __syncthreads();

        int ng = threadIdx.x & 15, og = threadIdx.x >> 4;
        float acc[4][2] = {{0.f, 0.f}, {0.f, 0.f}, {0.f, 0.f}, {0.f, 0.f}};
        for (int cc = 0; cc < 64; ++cc) {
            float pv[4];
            #pragma unroll
            for (int r = 0; r < 4; ++r) pv[r] = inl[(ng * 4 + r) * 65 + cc];
            float2 wv = *(const float2*)&wl[cc * 36 + og * 2];
            #pragma unroll
            for (int r = 0; r < 4; ++r) {
                acc[r][0] = fmaf(pv[r], wv.x, acc[r][0]);
                acc[r][1] = fmaf(pv[r], wv.y, acc[r][1]);
            }
        }
        __syncthreads();
        #pragma unroll
        for (int r = 0; r < 4; ++r) {
            wl[(ng * 4 + r) * 36 + og * 2 + 0] = acc[r][0];
            wl[(ng * 4 + r) * 36 + og * 2 + 1] = acc[r][1];
        }
        __syncthreads();
        float* dst = (which ? cfeat : afeat) + ((size_t)(b * 4096 + n0)) * 128 + o0;
        for (int idx = threadIdx.x; idx < 64 * 32; idx += 256) {
            int p = idx >> 5, o = idx & 31;
            dst[(size_t)p * 128 + o] = wl[p * 36 + o];
        }
    } else {
        // init: stats zero; min-extreme buffers get 0xFFFFFFFF sentinel
        for (int i = threadIdx.x; i < ST_COUNT; i += 256) {
            bool sentinel = (i >= (int)(RMN_GM - ST_BASE) && i < (int)(RMX_L2 - ST_BASE)) ||
                            (i >= (int)(RMN_L2 - ST_BASE));
            stz[i] = sentinel ? 0xFFFFFFFFu : 0u;
        }
    }
}

// ============================================================
// Kernel B: gather (1024) | L0 layer (256)
// ============================================================
__global__ __launch_bounds__(256) void kB(const float* __restrict__ afeat,
                                          const float* __restrict__ cfeat,
                                          const int* __restrict__ edges,
                                          float* __restrict__ M,
                                          float* __restrict__ stBN1,
                                          const float* __restrict__ xyz,
                                          const float* __restrict__ pts,
                                          const float* __restrict__ w0,
                                          const float* __restrict__ bias0,
                                          float* __restrict__ l0raw,
                                          float* __restrict__ stL0) {
    __shared__ __align__(16) unsigned char smem[35840];
    int u = blockIdx.x;
    if (u < 1024) {
        int* eL = (int*)smem;                       // 16*24
        float* red = (float*)(smem + 1536);         // 8*132
        int b, chunk;
        xcd_decode(u, b, chunk);                    // chunk in [0,256)
        int q0 = b * 4096 + chunk * 16;
        for (int idx = threadIdx.x; idx < 16 * KNN; idx += 256) eL[idx] = edges[(size_t)q0 * KNN + idx];
        __syncthreads();

        int m = threadIdx.x & 31;
        int g = threadIdx.x >> 5;
        int bbase = b << 12;
        float s1[4] = {0.f, 0.f, 0.f, 0.f}, s2[4] = {0.f, 0.f, 0.f, 0.f};

        #pragma unroll
        for (int half = 0; half < 2; ++half) {
            int p = g + half * 8;
            int q = q0 + p;
            float mx0 = -__builtin_inff(), mx1 = mx0, mx2 = mx0, mx3 = mx0;
            float sv0 = 0.f, sv1 = 0.f, sv2 = 0.f, sv3 = 0.f;
            float qv0 = 0.f, qv1 = 0.f, qv2 = 0.f, qv3 = 0.f;
            #pragma unroll 8
            for (int k = 0; k < KNN; ++k) {
                int e = eL[p * KNN + k];
                float4 v = *(const float4*)&cfeat[((size_t)(bbase + e) << 7) + m * 4];
                mx0 = fmaxf(mx0, v.x); sv0 += v.x; qv0 = fmaf(v.x, v.x, qv0);
                mx1 = fmaxf(mx1, v.y); sv1 += v.y; qv1 = fmaf(v.y, v.y, qv1);
                mx2 = fmaxf(mx2, v.z); sv2 += v.z; qv2 = fmaf(v.z, v.z, qv2);
                mx3 = fmaxf(mx3, v.w); sv3 += v.w; qv3 = fmaf(v.w, v.w, qv3);
            }
            float4 a = *(const float4*)&afeat[((size_t)q << 7) + m * 4];
            float4 mo = make_float4(a.x + mx0, a.y + mx1, a.z + mx2, a.w + mx3);
            *(float4*)&M[((size_t)q << 7) + m * 4] = mo;
            s1[0] += fmaf(24.f, a.x, sv0); s2[0] += 24.f * a.x * a.x + 2.f * a.x * sv0 + qv0;
            s1[1] += fmaf(24.f, a.y, sv1); s2[1] += 24.f * a.y * a.y + 2.f * a.y * sv1 + qv1;
            s1[2] += fmaf(24.f, a.z, sv2); s2[2] += 24.f * a.z * a.z + 2.f * a.z * sv2 + qv2;
            s1[3] += fmaf(24.f, a.w, sv3); s2[3] += 24.f * a.w * a.w + 2.f * a.w * sv3 + qv3;
        }
        #pragma unroll
        for (int j = 0; j < 4; ++j) red[g * 132 + m * 4 + j] = s1[j];
        __syncthreads();
        if (threadIdx.x < 128) {
            float t = 0.f;
            #pragma unroll
            for (int gg = 0; gg < 8; ++gg) t += red[gg * 132 + threadIdx.x];
            atomicAdd(&stBN1[threadIdx.x], t);
        }
        __syncthreads();
        #pragma unroll
        for (int j = 0; j < 4; ++j) red[g * 132 + m * 4 + j] = s2[j];
        __syncthreads();
        if (threadIdx.x < 128) {
            float t = 0.f;
            #pragma unroll
            for (int gg = 0; gg < 8; ++gg) t += red[gg * 132 + threadIdx.x];
            atomicAdd(&stBN1[128 + threadIdx.x], t);
        }
    } else {
        int v = u - 1024;
        int b, chunk;
        xcd_decode(v, b, chunk);            // chunk in [0,64)
        layer_part<67, 64, 64, 0, true, true, false>(smem, b, chunk, 0,
            nullptr, nullptr, 0.f, nullptr, nullptr,
            w0, bias0, xyz, pts, l0raw, stL0, nullptr, nullptr);
    }
}

// ============================================================
// Kernel C: GM layer (256, minmax) | L1 layer (256)
// ============================================================
__global__ __launch_bounds__(256) void kC(const float* __restrict__ M,
                                          const float* __restrict__ stBN1,
                                          const float* __restrict__ ec_g,
                                          const float* __restrict__ ec_b,
                                          const float* __restrict__ gm_w,
                                          float* __restrict__ stGM,
                                          unsigned* __restrict__ rmxGM,
                                          unsigned* __restrict__ rmnGM,
                                          const float* __restrict__ l0raw,
                                          const float* __restrict__ stL0,
                                          const float* __restrict__ g0,
                                          const float* __restrict__ be0,
                                          const float* __restrict__ w1,
                                          const float* __restrict__ bias1,
                                          float* __restrict__ l1raw,
                                          float* __restrict__ stL1) {
    __shared__ __align__(16) unsigned char smem[52224];
    int u = blockIdx.x;
    if (u < 256) {
        int b, chunk;
        xcd_decode(u, b, chunk);
        layer_part<128, 128, 128, 2, false, false, true>(smem, b, chunk, 0,
            M, stBN1, 1.0f / 393216.0f, ec_g, ec_b,
            gm_w, nullptr, nullptr, nullptr, nullptr, stGM, rmxGM, rmnGM);
    } else {
        int v = u - 256;
        int b, chunk;
        xcd_decode(v, b, chunk);
        layer_part<64, 128, 128, 1, true, true, false>(smem, b, chunk, 0,
            l0raw, stL0, 1.0f / 16384.0f, g0, be0,
            w1, bias1, nullptr, nullptr, l1raw, stL1, nullptr, nullptr);
    }
}

// ============================================================
// Kernel D: L2 layer (512, minmax, no raw output)
// ============================================================
__global__ __launch_bounds__(256) void kD(const float* __restrict__ l1raw,
                                          const float* __restrict__ stL1,
                                          const float* __restrict__ g1,
                                          const float* __restrict__ be1,
                                          const float* __restrict__ w2,
                                          const float* __restrict__ bias2,
                                          float* __restrict__ stL2,
                                          unsigned* __restrict__ rmxL2,
                                          unsigned* __restrict__ rmnL2) {
    __shared__ __align__(16) unsigned char smem[52224];
    int u = blockIdx.x;
    int b, t;
    xcd_decode(u, b, t);                    // t in [0,128)
    int chunk = t & 63, y = t >> 6;
    layer_part<128, 256, 128, 1, true, false, true>(smem, b, chunk, y * 128,
        l1raw, stL1, 1.0f / 16384.0f, g1, be1,
        w2, bias2, nullptr, nullptr, nullptr, stL2, rmxL2, rmnL2);
}

// ============================================================
// Kernel E (1 block): BN consts -> act at raw extremes (exact
// monotone pushthrough) -> fused 384-feature -> final head.
// ============================================================
__global__ __launch_bounds__(256) void kE(const float* __restrict__ stGM,
                                          const float* __restrict__ gm_g,
                                          const float* __restrict__ gm_b,
                                          const unsigned* __restrict__ rmxGM,
                                          const unsigned* __restrict__ rmnGM,
                                          const float* __restrict__ stL2,
                                          const float* __restrict__ g2,
                                          const float* __restrict__ be2,
                                          const unsigned* __restrict__ rmxL2,
                                          const unsigned* __restrict__ rmnL2,
                                          const float* __restrict__ fu_w,
                                          const float* __restrict__ fu_g,
                                          const float* __restrict__ fu_b,
                                          float* __restrict__ out) {
    __shared__ float fl[4 * 384];
    const float rc = 1.0f / 16384.0f;
    int t = threadIdx.x;
    {   // point branch (relu): O=256
        int o = t;
        float m = stL2[o] * rc;
        float v = stL2[256 + o] * rc - m * m;
        float sc = g2[o] / sqrtf(v + 1e-5f);
        float sh = be2[o] - m * sc;
        #pragma unroll
        for (int b = 0; b < 4; ++b) {
            float f1 = fmaxf(fmaf(funmap(rmxL2[b * 256 + o]), sc, sh), 0.f);
            float f2 = fmaxf(fmaf(funmap(rmnL2[b * 256 + o]), sc, sh), 0.f);
            fl[b * 384 + o] = fmaxf(f1, f2);
        }
    }
    if (t < 128) {   // graph branch (leaky): O=128
        int o = t;
        float m = stGM[o] * rc;
        float v = stGM[128 + o] * rc - m * m;
        float sc = gm_g[o] / sqrtf(v + 1e-5f);
        float sh = gm_b[o] - m * sc;
        #pragma unroll
        for (int b = 0; b < 4; ++b) {
            float x1 = fmaf(funmap(rmxGM[b * 128 + o]), sc, sh);
            x1 = (x1 > 0.f) ? x1 : 0.2f * x1;
            float x2 = fmaf(funmap(rmnGM[b * 128 + o]), sc, sh);
            x2 = (x2 > 0.f) ? x2 : 0.2f * x2;
            fl[b * 384 + 256 + o] = fmaxf(x1, x2);
        }
    }
    __syncthreads();
    int o = t;
    float f[4];
    #pragma unroll
    for (int bb = 0; bb < 4; ++bb) {
        float acc = 0.f;
        for (int c = 0; c < 384; ++c) acc = fmaf(fl[bb * 384 + c], fu_w[(size_t)o * 384 + c], acc);
        f[bb] = acc;
    }
    float m = 0.25f * (f[0] + f[1] + f[2] + f[3]);
    float var = 0.f;
    #pragma unroll
    for (int bb = 0; bb < 4; ++bb) { float tt = f[bb] - m; var = fmaf(tt, tt, var); }
    var *= 0.25f;
    float inv = 1.0f / sqrtf(var + 1e-5f);
    float gv = fu_g[o], bv = fu_b[o];
    #pragma unroll
    for (int bb = 0; bb < 4; ++bb) {
        float xx = (f[bb] - m) * inv * gv + bv;
        xx = (xx > 0.0f) ? xx : 0.2f * xx;
        out[bb * 256 + o] = xx;
    }
}

extern "C" void kernel_launch(void* const* d_in, const int* in_sizes, int n_in,
                              void* d_out, int out_size, void* d_ws, size_t ws_size,
                              hipStream_t stream) {
    const float* xyz   = (const float*)d_in[0];
    const float* pts   = (const float*)d_in[1];
    const float* ec_w  = (const float*)d_in[2];
    const float* ec_g  = (const float*)d_in[3];
    const float* ec_b  = (const float*)d_in[4];
    const float* gm_w  = (const float*)d_in[5];
    const float* gm_g  = (const float*)d_in[6];
    const float* gm_b  = (const float*)d_in[7];
    const float* w0    = (const float*)d_in[8];
    const float* bias0 = (const float*)d_in[9];
    const float* g0    = (const float*)d_in[10];
    const float* be0   = (const float*)d_in[11];
    const float* w1    = (const float*)d_in[12];
    const float* bias1 = (const float*)d_in[13];
    const float* g1    = (const float*)d_in[14];
    const float* be1   = (const float*)d_in[15];
    const float* w2    = (const float*)d_in[16];
    const float* bias2 = (const float*)d_in[17];
    const float* g2    = (const float*)d_in[18];
    const float* be2   = (const float*)d_in[19];
    const float* fu_w  = (const float*)d_in[20];
    const float* fu_g  = (const float*)d_in[21];
    const float* fu_b  = (const float*)d_in[22];

    float* ws = (float*)d_ws;
    float* out = (float*)d_out;

    kA<<<6145, 256, 0, stream>>>(xyz, pts, ec_w, (int*)(ws + OFF_EDGES),
                                 ws + OFF_A, ws + OFF_C, (unsigned*)(ws + ST_BASE));
    kB<<<1280, 256, 0, stream>>>(ws + OFF_A, ws + OFF_C, (int*)(ws + OFF_EDGES),
                                 ws + OFF_M, ws + ST_BN1,
                                 xyz, pts, w0, bias0, ws + OFF_L0, ws + ST_L0);
    kC<<<512, 256, 0, stream>>>(ws + OFF_M, ws + ST_BN1, ec_g, ec_b, gm_w,
                                ws + ST_GM, (unsigned*)(ws + RMX_GM), (unsigned*)(ws + RMN_GM),
                                ws + OFF_L0, ws + ST_L0, g0, be0, w1, bias1,
                                ws + OFF_L1, ws + ST_L1);
    kD<<<512, 256, 0, stream>>>(ws + OFF_L1, ws + ST_L1, g1, be1, w2, bias2,
                                ws + ST_L2, (unsigned*)(ws + RMX_L2), (unsigned*)(ws + RMN_L2));
    kE<<<1, 256, 0, stream>>>(ws + ST_GM, gm_g, gm_b,
                              (unsigned*)(ws + RMX_GM), (unsigned*)(ws + RMN_GM),
                              ws + ST_L2, g2, be2,
                              (unsigned*)(ws + RMX_L2), (unsigned*)(ws + RMN_L2),
                              fu_w, fu_g, fu_b, out);
}